// Round 9
// baseline (1139.212 us; speedup 1.0000x reference)
//
#include <hip/hip_runtime.h>
#include <hip/hip_bf16.h>

// Problem constants
#define B_ 128
#define L_ 105
#define M_ 55
#define D_ 256
#define NCOMBO 18   // 3 patches x 2 branches x 3 layers

// Workspace layout (float offsets)
#define WS_XT    0          // normalized x^T: [B*M][105] = 739200
#define WS_PE    739200     // pos-embed tables: 86*256 = 22016
#define WS_LEFT  761216     // 18 * 27648 (fallback path; MP overlays after mm)
#define WS_RIGHT 1258880    // 18 * 27648 (ACC overlays after mm)
#define WS_MM    1756544    // 18 * 11664
#define WS_MP    761216     // 18 * 12544 (over LEFT, after mm)
#define WS_ACC   1258880    // 758016 floats (over RIGHT + MM tail)
#define LR_STRIDE 27648
#define MM_STRIDE 11664
#define MP_STRIDE 12544
#define ACC_TOT  758016

// K-split partial region (only used when ws_size is large enough)
#define WS_LRP        1966592
#define LRP_KZ_STRIDE 27648
#define LRP_C_STRIDE  110592
#define LRP_HALF      1990656
#define WS_NEED_BYTES ((size_t)(WS_LRP + 2 * LRP_HALF) * 4)

__constant__ int c_peOff[6] = {0, 35, 38, 59, 64, 79};
__constant__ int c_accbase[18] = {0,1225,2450, 3675,3684,3693, 3702,4143,4584,
                                  5025,5050,5075, 5100,5325,5550, 5775,5824,5873};

__device__ __forceinline__ void combo_dims(int c, int& i, int& br, int& l,
                                           int& p, int& n, int& Cin, int& T, int& J) {
    i = c / 6; br = (c % 6) / 3; l = c % 3;
    p = 3 + 2 * i;
    n = L_ / p;
    Cin = br ? n : p;
    T   = br ? p : n;
    J = 3 * Cin;
}

__device__ __forceinline__ float dot4(float4 a, float4 b) {
    return a.x * b.x + a.y * b.y + a.z * b.z + a.w * b.w;
}

// ---------------- RevIN normalize ----------------
__global__ void revin_kernel(const float* __restrict__ x, float* __restrict__ ws) {
    int bm = blockIdx.x; int b = bm / M_; int m = bm % M_;
    int tid = threadIdx.x;
    __shared__ float s1[128], s2[128];
    float v = 0.f;
    if (tid < L_) v = x[(b * L_ + tid) * M_ + m];
    s1[tid] = v; s2[tid] = v * v;
    __syncthreads();
    for (int off = 64; off > 0; off >>= 1) {
        if (tid < off) { s1[tid] += s1[tid + off]; s2[tid] += s2[tid + off]; }
        __syncthreads();
    }
    float mean = s1[0] * (1.f / L_);
    float var  = s2[0] * (1.f / L_) - mean * mean;
    float rstd = rsqrtf(var + 1e-5f);
    if (tid < L_) ws[WS_XT + bm * L_ + tid] = (v - mean) * rstd;
}

// ---------------- Positional embedding tables ----------------
__global__ void pe_kernel(float* __restrict__ ws) {
    int bi = blockIdx.x;
    int i = bi / 2, br = bi % 2;
    int p = 3 + 2 * i, n = L_ / p;
    int T = br ? p : n;
    int d = threadIdx.x;
    float divv = expf(-(float)(d & ~1) * (logf(10000.f) / (float)D_));
    float* base = ws + WS_PE + c_peOff[bi] * D_;
    for (int t = 0; t < T; ++t) {
        float arg = (float)t * divv;
        base[t * D_ + d] = (d & 1) ? cosf(arg) : sinf(arg);
    }
}

// ---------------- lr2: K-split x4, 8-row tiles, unique-writer partials ----------------
__global__ __launch_bounds__(256) void lr2_kernel(
                          const float* __restrict__ w0, const float* __restrict__ w1,
                          const float* __restrict__ w2c, const float* __restrict__ w3,
                          const float* __restrict__ w4, const float* __restrict__ w5,
                          const float* __restrict__ Wq, const float* __restrict__ bq,
                          const float* __restrict__ Wk, const float* __restrict__ bk,
                          float* __restrict__ ws) {
    int c = blockIdx.x;
    int i, br, l, p, n, Cin, T, J; combo_dims(c, i, br, l, p, n, Cin, T, J);
    int Mdim = J + T;
    int r0 = blockIdx.y * 8;
    if (r0 >= Mdim) return;
    int kz = blockIdx.z;
    int d0 = kz * 64;
    int wi = i * 2 + br;
    const float* conv = (wi == 0) ? w0 : (wi == 1) ? w1 : (wi == 2) ? w2c
                       : (wi == 3) ? w3 : (wi == 4) ? w4 : w5;
    __shared__ float S[8][64];
    int tid = threadIdx.x;
    for (int idx = tid; idx < 8 * 64; idx += 256) {
        int rr = idx >> 6, dd = idx & 63;
        int row = r0 + rr; float val = 0.f;
        int d = d0 + dd;
        if (row < J) val = conv[d * J + row];
        else if (row < Mdim) val = ws[WS_PE + (c_peOff[wi] + (row - J)) * D_ + d];
        S[rr][dd] = val;
    }
    __syncthreads();
    const float* wqp = Wq + l * D_ * D_;
    const float* wkp = Wk + l * D_ * D_;
    float accL[8], accR[8];
#pragma unroll
    for (int rr = 0; rr < 8; ++rr) { accL[rr] = 0.f; accR[rr] = 0.f; }
    int o = tid;
#pragma unroll 8
    for (int dd = 0; dd < 64; ++dd) {
        int d = d0 + dd;
        float wqv = wqp[d * D_ + o];
        float wkv = wkp[d * D_ + o];
#pragma unroll
        for (int rr = 0; rr < 8; ++rr) {
            float sv = S[rr][dd];
            accL[rr] += sv * wqv;
            accR[rr] += sv * wkv;
        }
    }
    float bqv = (kz == 0) ? bq[l * D_ + o] : 0.f;
    float bkv = (kz == 0) ? bk[l * D_ + o] : 0.f;
    float* Lp = ws + WS_LRP + c * LRP_C_STRIDE + kz * LRP_KZ_STRIDE;
    float* Rp = Lp + LRP_HALF;
#pragma unroll
    for (int rr = 0; rr < 8; ++rr) {
        int row = r0 + rr;
        if (row < Mdim) {
            float aq = (row >= J) ? bqv : 0.f;
            float ak = (row >= J) ? bkv : 0.f;
            Lp[row * D_ + o] = accL[rr] + aq;
            Rp[row * D_ + o] = accR[rr] + ak;
        }
    }
}

// ---------------- Fallback lr: 4 rows per block, full K ----------------
__global__ __launch_bounds__(256) void lr_kernel(
                          const float* __restrict__ w0, const float* __restrict__ w1,
                          const float* __restrict__ w2c, const float* __restrict__ w3,
                          const float* __restrict__ w4, const float* __restrict__ w5,
                          const float* __restrict__ Wq, const float* __restrict__ bq,
                          const float* __restrict__ Wk, const float* __restrict__ bk,
                          float* __restrict__ ws) {
    int c = blockIdx.x;
    int i, br, l, p, n, Cin, T, J; combo_dims(c, i, br, l, p, n, Cin, T, J);
    int Mdim = J + T;
    int r0 = blockIdx.y * 4;
    if (r0 >= Mdim) return;
    int wi = i * 2 + br;
    const float* conv = (wi == 0) ? w0 : (wi == 1) ? w1 : (wi == 2) ? w2c
                       : (wi == 3) ? w3 : (wi == 4) ? w4 : w5;
    __shared__ float S[4][256];
    int tid = threadIdx.x;
    for (int idx = tid; idx < 4 * 256; idx += 256) {
        int rr = idx >> 8, dd = idx & 255;
        int row = r0 + rr; float val = 0.f;
        if (row < J) val = conv[dd * J + row];
        else if (row < Mdim) val = ws[WS_PE + (c_peOff[wi] + (row - J)) * D_ + dd];
        S[rr][dd] = val;
    }
    __syncthreads();
    const float* wqp = Wq + l * D_ * D_;
    const float* wkp = Wk + l * D_ * D_;
    float accL[4], accR[4];
#pragma unroll
    for (int rr = 0; rr < 4; ++rr) { accL[rr] = 0.f; accR[rr] = 0.f; }
    int o = tid;
#pragma unroll 8
    for (int d = 0; d < D_; ++d) {
        float wqv = wqp[d * D_ + o];
        float wkv = wkp[d * D_ + o];
#pragma unroll
        for (int rr = 0; rr < 4; ++rr) {
            float sv = S[rr][d];
            accL[rr] += sv * wqv;
            accR[rr] += sv * wkv;
        }
    }
    float bqv = bq[l * D_ + o], bkv = bk[l * D_ + o];
#pragma unroll
    for (int rr = 0; rr < 4; ++rr) {
        int row = r0 + rr;
        if (row < Mdim) {
            float aq = (row >= J) ? bqv : 0.f;
            float ak = (row >= J) ? bkv : 0.f;
            ws[WS_LEFT  + c * LR_STRIDE + row * D_ + o] = accL[rr] + aq;
            ws[WS_RIGHT + c * LR_STRIDE + row * D_ + o] = accR[rr] + ak;
        }
    }
}

// ---------------- M' = Left @ Right^T (sums K-split partials when enabled) ------------
__global__ void mm_kernel(float* __restrict__ ws, int use_partial) {
    int c = blockIdx.x;
    int i, br, l, p, n, Cin, T, J; combo_dims(c, i, br, l, p, n, Cin, T, J);
    int Mdim = J + T;
    int tr = blockIdx.y / 7, tc = blockIdx.y % 7;
    int r0 = tr * 16, c0 = tc * 16;
    if (r0 >= Mdim || c0 >= Mdim) return;
    __shared__ __align__(16) float Lb[16][260], Rb[16][260];
    int tid = threadIdx.x;
    if (use_partial) {
        const float* Lp = ws + WS_LRP + c * LRP_C_STRIDE;
        const float* Rp = Lp + LRP_HALF;
        for (int idx = tid; idx < 16 * 256; idx += 256) {
            int rr = idx >> 8, d = idx & 255;
            int rL = r0 + rr, rR = c0 + rr;
            float lv = 0.f, rv = 0.f;
            if (rL < Mdim) {
                int base = rL * D_ + d;
                lv = Lp[base] + Lp[base + LRP_KZ_STRIDE]
                   + Lp[base + 2 * LRP_KZ_STRIDE] + Lp[base + 3 * LRP_KZ_STRIDE];
            }
            if (rR < Mdim) {
                int base = rR * D_ + d;
                rv = Rp[base] + Rp[base + LRP_KZ_STRIDE]
                   + Rp[base + 2 * LRP_KZ_STRIDE] + Rp[base + 3 * LRP_KZ_STRIDE];
            }
            Lb[rr][d] = lv; Rb[rr][d] = rv;
        }
    } else {
        for (int idx = tid; idx < 16 * 256; idx += 256) {
            int rr = idx >> 8, d = idx & 255;
            int rL = r0 + rr, rR = c0 + rr;
            Lb[rr][d] = (rL < Mdim) ? ws[WS_LEFT  + c * LR_STRIDE + rL * D_ + d] : 0.f;
            Rb[rr][d] = (rR < Mdim) ? ws[WS_RIGHT + c * LR_STRIDE + rR * D_ + d] : 0.f;
        }
    }
    __syncthreads();
    int rr = tid / 16, cc = tid % 16;
    const float4* lrow = (const float4*)(&Lb[rr][0]);
    const float4* rrow = (const float4*)(&Rb[cc][0]);
    float acc = 0.f;
#pragma unroll 8
    for (int d4 = 0; d4 < 64; ++d4) {
        float4 a = lrow[d4], bb = rrow[d4];
        acc += a.x * bb.x + a.y * bb.y + a.z * bb.z + a.w * bb.w;
    }
    int r = r0 + rr, cth = c0 + cc;
    if (r < Mdim && cth < Mdim)
        ws[WS_MM + c * MM_STRIDE + r * Mdim + cth] = acc;
}

// ---------------- Pack M' into reordered/padded Mp [W x W] per combo ----------------
__global__ void pack_kernel(float* __restrict__ ws) {
    int c = blockIdx.x;
    int i, br, l, p, n, Cin, T, J; combo_dims(c, i, br, l, p, n, Cin, T, J);
    int Mdim = J + T;
    int Cinp = (Cin + 3) & ~3;
    int Jp = 3 * Cinp;
    int T4 = (T + 3) & ~3;
    int W = Jp + T4;
    const float* MMc = ws + WS_MM + c * MM_STRIDE;
    float* Mp = ws + WS_MP + c * MP_STRIDE;
    for (int e = threadIdx.x; e < W * W; e += 256) {
        int r = e / W, o = e % W;
        int srcr = -1, srcc = -1;
        bool brow = false;
        if (r < Jp) {
            int k = r / Cinp, cin = r % Cinp;
            if (cin < Cin) srcr = cin * 3 + k;
        } else {
            int t = r - Jp;
            if (t < T) { srcr = J + t; brow = true; }
        }
        if (o < Jp) {
            int k2 = o / Cinp, cin2 = o % Cinp;
            if (cin2 < Cin) srcc = cin2 * 3 + k2;
        } else {
            int s = o - Jp;
            if (s < T) srcc = J + s;
        }
        float val;
        if (srcr >= 0 && srcc >= 0) val = MMc[srcr * Mdim + srcc];
        else if (brow && o >= Jp && srcc < 0) val = -1e30f;  // padded-s bias: kill in softmax
        else val = 0.f;
        Mp[e] = val;
    }
}

// ---------------- Zero the atomic accumulator region ----------------
__global__ void zero_acc(float* __restrict__ ws) {
    int idx = blockIdx.x * 256 + threadIdx.x;
    if (idx < ACC_TOT / 4) {
        float4 z; z.x = 0.f; z.y = 0.f; z.z = 0.f; z.w = 0.f;
        ((float4*)(ws + WS_ACC))[idx] = z;
    }
}

// ---------------- attn3: BR=0 (patch-size branch), R-unified, register softmax --------
template<int P>
__global__ __launch_bounds__(256) void attn3(const float* __restrict__ ws,
                                             float* __restrict__ wsw) {
    constexpr int T    = L_ / P;           // 35,21,15
    constexpr int Cin  = P;
    constexpr int Cinp = (Cin + 3) & ~3;   // 4,8,8
    constexpr int Jp   = 3 * Cinp;         // 12,24,24
    constexpr int JpF4 = Jp / 4;           // 3,6,6
    constexpr int T4   = (T + 3) & ~3;     // 36,24,16
    constexpr int W    = Jp + T4;          // 48,48,40
    constexpr int W4   = W / 4;            // 12,12,10
    constexpr int GS4  = W4 | 1;           // odd f4 stride: 13,13,11
    constexpr int RS4  = JpF4 | 1;         // 3,7,7
    constexpr int RSfl = RS4 * 4;
    constexpr int SSf4 = (T4 / 4) | 1;     // 9,7,5
    constexpr int SSfl = SSf4 * 4;
    constexpr int MC   = (P == 3) ? 4 : (P == 5 ? 5 : 8);
    constexpr int II   = (P - 3) / 2;
    constexpr int PRS  = (T + 1) / 2;      // row-pairs per mc
    // LDS: | R | G (sx staged here first) | SP (MpS during G, probs after) |
    constexpr int OFF_R  = 0;
    constexpr int R_SZ   = MC * T4 * RSfl;
    constexpr int OFF_G  = OFF_R + R_SZ;
    constexpr int G_SZ   = MC * T4 * GS4 * 4;
    constexpr int OFF_SP = OFF_G + G_SZ;
    constexpr int SP_SZ  = (W * W > MC * T * SSfl) ? (W * W) : (MC * T * SSfl);
    constexpr int TOT    = OFF_SP + SP_SZ;
    static_assert(TOT * 4 <= 65536, "LDS budget");
    static_assert(G_SZ >= MC * 105, "sx staging fits in G region");

    __shared__ __align__(16) float smem[TOT];
    const int tid = threadIdx.x;
    const int b = blockIdx.x, l = blockIdx.y, sp = blockIdx.z;
    const int c = II * 6 + l;              // BR=0
    const int m0 = sp * MC;
    const int vm = (M_ - m0 < MC) ? (M_ - m0) : MC;

    const float4* Mpg4 = (const float4*)(ws + WS_MP + c * MP_STRIDE);
    float* sx = smem + OFF_G;              // [MC][105] staging (dead after R build)
    float4* SP4 = (float4*)(smem + OFF_SP);
    const float4* R4 = (const float4*)(smem + OFF_R);
    float4* G4 = (float4*)(smem + OFF_G);

    // ---- stage sx + MpS ----
    for (int e = tid; e < MC * 105; e += 256) {
        int mc = e / 105, z = e % 105;
        sx[e] = (m0 + mc < M_) ? ws[WS_XT + (size_t)(b * M_ + m0 + mc) * L_ + z] : 0.f;
    }
    for (int e = tid; e < (W * W) / 4; e += 256)
        SP4[e] = Mpg4[e];
    __syncthreads();

    // ---- build R [MC][T4][RSfl] ----
    for (int e = tid; e < MC * T4 * RSfl; e += 256) {
        int mc = e / (T4 * RSfl);
        int r  = e % (T4 * RSfl);
        int t = r / RSfl, j = r % RSfl;
        float val = 0.f;
        if (t < T && j < Jp) {
            int k = j / Cinp, cin = j % Cinp;
            if (cin < Cin) {
                int tp = t + k - 1;
                if (tp < 0) tp += T;
                if (tp >= T) tp -= T;
                val = sx[mc * 105 + tp * Cin + cin];
            }
        }
        smem[OFF_R + e] = val;
    }
    __syncthreads();

    // ---- G-phase: G = R @ MpS[0:Jp] + bias rows; 4rows x 4cols register tiles ----
    constexpr int NT  = (MC * T4 / 4) * W4;
    constexpr int TPB = (NT + 255) / 256;
#pragma unroll
    for (int tt = 0; tt < TPB; ++tt) {
        int q = tid + tt * 256;
        if (q < NT) {
            int o4 = q % W4, rt = q / W4;
            int rbase = rt * 4;            // global row = mc*T4 + t, aligned (T4 % 4 == 0)
            float4 acc[4];
#pragma unroll
            for (int a = 0; a < 4; ++a) {
                int t = (rbase + a) % T4;
                acc[a] = SP4[(Jp + t) * W4 + o4];   // bias row from Mp
            }
#pragma unroll
            for (int j4 = 0; j4 < JpF4; ++j4) {
                float4 rr[4], mp[4];
#pragma unroll
                for (int a = 0; a < 4; ++a)
                    rr[a] = R4[(rbase + a) * RS4 + j4];
#pragma unroll
                for (int jj = 0; jj < 4; ++jj)
                    mp[jj] = SP4[(j4 * 4 + jj) * W4 + o4];
#pragma unroll
                for (int a = 0; a < 4; ++a) {
#pragma unroll
                    for (int jj = 0; jj < 4; ++jj) {
                        float rv = (jj == 0) ? rr[a].x : (jj == 1) ? rr[a].y
                                 : (jj == 2) ? rr[a].z : rr[a].w;
                        acc[a].x += rv * mp[jj].x;
                        acc[a].y += rv * mp[jj].y;
                        acc[a].z += rv * mp[jj].z;
                        acc[a].w += rv * mp[jj].w;
                    }
                }
            }
#pragma unroll
            for (int a = 0; a < 4; ++a)
                G4[(rbase + a) * GS4 + o4] = acc[a];
        }
    }
    __syncthreads();

    // ---- S-phase: 2 G-rows per thread, register softmax, store probs to SP ----
    if (tid < MC * PRS) {
        int mc = tid / PRS, pq = tid % PRS;
        int t0 = pq * 2;
        bool h1 = (t0 + 1 < T);
        float4 gj0[JpF4], gj1[JpF4];
#pragma unroll
        for (int j4 = 0; j4 < JpF4; ++j4) {
            gj0[j4] = G4[(mc * T4 + t0) * GS4 + j4];
            gj1[j4] = G4[(mc * T4 + t0 + 1) * GS4 + j4];
        }
        float pr0[T4], pr1[T4];
#pragma unroll
        for (int s4 = 0; s4 < T4 / 4; ++s4) {
            float4 i0 = G4[(mc * T4 + t0) * GS4 + JpF4 + s4];
            float4 i1 = G4[(mc * T4 + t0 + 1) * GS4 + JpF4 + s4];
            pr0[s4 * 4 + 0] = i0.x; pr0[s4 * 4 + 1] = i0.y;
            pr0[s4 * 4 + 2] = i0.z; pr0[s4 * 4 + 3] = i0.w;
            pr1[s4 * 4 + 0] = i1.x; pr1[s4 * 4 + 1] = i1.y;
            pr1[s4 * 4 + 2] = i1.z; pr1[s4 * 4 + 3] = i1.w;
        }
#pragma unroll
        for (int s = 0; s < T4; ++s) {
            float a0 = pr0[s], a1 = pr1[s];
#pragma unroll
            for (int j4 = 0; j4 < JpF4; ++j4) {
                float4 rv = R4[(mc * T4 + s) * RS4 + j4];
                a0 += dot4(gj0[j4], rv);
                a1 += dot4(gj1[j4], rv);
            }
            pr0[s] = a0; pr1[s] = a1;
        }
        // scale + softmax in registers (pads carry -1e30 bias -> exp = 0)
        float mx0 = -1e30f, mx1 = -1e30f;
#pragma unroll
        for (int s = 0; s < T4; ++s) {
            pr0[s] *= 0.0625f; pr1[s] *= 0.0625f;
            mx0 = fmaxf(mx0, pr0[s]); mx1 = fmaxf(mx1, pr1[s]);
        }
        float sum0 = 0.f, sum1 = 0.f;
#pragma unroll
        for (int s = 0; s < T4; ++s) {
            pr0[s] = __expf(pr0[s] - mx0); sum0 += pr0[s];
            pr1[s] = __expf(pr1[s] - mx1); sum1 += pr1[s];
        }
        float inv0 = 1.f / sum0, inv1 = 1.f / sum1;
        float4* SPs = (float4*)(smem + OFF_SP);
#pragma unroll
        for (int s4 = 0; s4 < T4 / 4; ++s4) {
            float4 o0;
            o0.x = pr0[s4 * 4 + 0] * inv0; o0.y = pr0[s4 * 4 + 1] * inv0;
            o0.z = pr0[s4 * 4 + 2] * inv0; o0.w = pr0[s4 * 4 + 3] * inv0;
            SPs[(mc * T + t0) * SSf4 + s4] = o0;
        }
        if (h1) {
#pragma unroll
            for (int s4 = 0; s4 < T4 / 4; ++s4) {
                float4 o1;
                o1.x = pr1[s4 * 4 + 0] * inv1; o1.y = pr1[s4 * 4 + 1] * inv1;
                o1.z = pr1[s4 * 4 + 2] * inv1; o1.w = pr1[s4 * 4 + 3] * inv1;
                SPs[(mc * T + t0 + 1) * SSf4 + s4] = o1;
            }
        }
    }
    __syncthreads();

    // ---- deterministic in-block mc-sum, one atomic per cell ----
    float* accp = wsw + WS_ACC + c_accbase[c] * 128 + b * T * T;
    for (int e = tid; e < T * T; e += 256) {
        int t = e / T, s = e % T;
        float v = 0.f;
        for (int mc = 0; mc < vm; ++mc)
            v += smem[OFF_SP + (mc * T + t) * SSfl + s];
        atomicAdd(&accp[e], v);
    }
}

// ---------------- attn2 (BR=1 path, round-8 proven) ----------------
template<int P, int BR>
__global__ __launch_bounds__(256) void attn2(const float* __restrict__ ws,
                                             float* __restrict__ wsw) {
    constexpr int N    = L_ / P;
    constexpr int Cin  = BR ? N : P;
    constexpr int T    = BR ? P : N;
    constexpr int Cinp = (Cin + 3) & ~3;
    constexpr int Jp   = 3 * Cinp;
    constexpr int T4   = (T + 3) & ~3;
    constexpr int W    = Jp + T4;
    constexpr int W4   = W / 4;
    constexpr int ST   = T4 + 1;
    constexpr int II   = (P - 3) / 2;
    constexpr int MC   = BR ? (P == 3 ? 12 : 8) : (P == 7 ? 8 : 4);
    constexpr int NT   = (MC / 4) * T * W4;
    constexpr int TPB  = (NT + 255) / 256;
    constexpr int MCQ  = MC / 4;
    constexpr int CQ   = Cinp / 4;
    constexpr int S4N  = T4 / 4;
    constexpr int OFF_X2T = 0;
    constexpr int OFF_X2A = OFF_X2T + T * Cinp * MC;
    constexpr int OFF_MSL = OFF_X2A + T * Cinp * MC;
    constexpr int OFF_G   = OFF_MSL + Cinp * W;
    constexpr int OFF_S   = OFF_G + MC * T * W;
    constexpr int TOT     = OFF_S + MC * T * ST;
    static_assert(TOT * 4 <= 65536, "LDS budget");

    __shared__ __align__(16) float smem[TOT];
    const int tid = threadIdx.x;
    const int b = blockIdx.x, l = blockIdx.y, sp = blockIdx.z;
    const int c = II * 6 + BR * 3 + l;
    const int m0 = sp * MC;
    const int vm = (M_ - m0 < MC) ? (M_ - m0) : MC;

    const float*  Mpg  = ws + WS_MP + c * MP_STRIDE;
    const float4* Mpg4 = (const float4*)Mpg;

    for (int e = tid; e < T * Cinp * MC; e += 256) {
        int mcol = e % MC, rest = e / MC;
        int cin = rest % Cinp, trow = rest / Cinp;
        float v = 0.f;
        if (cin < Cin && m0 + mcol < M_)
            v = ws[WS_XT + (size_t)(b * M_ + m0 + mcol) * L_ + trow * Cin + cin];
        smem[OFF_X2T + e] = v;
    }
    for (int e = tid; e < T * Cinp * MC; e += 256) {
        int cin = e % Cinp, trow = (e / Cinp) % T, mcol = e / (Cinp * T);
        float v = 0.f;
        if (cin < Cin && m0 + mcol < M_)
            v = ws[WS_XT + (size_t)(b * M_ + m0 + mcol) * L_ + trow * Cin + cin];
        smem[OFF_X2A + e] = v;
    }

    const float4* X2T4 = (const float4*)(smem + OFF_X2T);
    const float4* X2A4 = (const float4*)(smem + OFF_X2A);
    float4*       MSL4 = (float4*)(smem + OFF_MSL);
    float4*       G4w  = (float4*)(smem + OFF_G);
    const float4* G4   = (const float4*)(smem + OFF_G);

    float a[TPB][4][4];
#pragma unroll
    for (int tt = 0; tt < TPB; ++tt) {
        int q = tid + tt * 256;
        if (q < NT) {
            int o4 = q % W4, t = (q / W4) % T;
            float4 bv = Mpg4[(Jp + t) * W4 + o4];
#pragma unroll
            for (int am = 0; am < 4; ++am) {
                a[tt][am][0] = bv.x; a[tt][am][1] = bv.y;
                a[tt][am][2] = bv.z; a[tt][am][3] = bv.w;
            }
        }
    }
    __syncthreads();
    for (int k = 0; k < 3; ++k) {
        for (int e = tid; e < Cinp * W4; e += 256)
            MSL4[e] = Mpg4[k * Cinp * W4 + e];
        __syncthreads();
#pragma unroll
        for (int tt = 0; tt < TPB; ++tt) {
            int q = tid + tt * 256;
            if (q < NT) {
                int o4 = q % W4, t = (q / W4) % T, m4 = q / (W4 * T);
                int trow = t + k - 1;
                if (trow < 0) trow += T;
                if (trow >= T) trow -= T;
                const float4* xp = X2T4 + trow * Cinp * MCQ + m4;
                const float4* mp = MSL4 + o4;
#pragma unroll 4
                for (int cin = 0; cin < Cinp; ++cin) {
                    float4 x4 = xp[cin * MCQ];
                    float4 mv = mp[cin * W4];
#pragma unroll
                    for (int aq = 0; aq < 4; ++aq) {
                        float m = (aq == 0) ? mv.x : (aq == 1) ? mv.y : (aq == 2) ? mv.z : mv.w;
                        a[tt][0][aq] += x4.x * m;
                        a[tt][1][aq] += x4.y * m;
                        a[tt][2][aq] += x4.z * m;
                        a[tt][3][aq] += x4.w * m;
                    }
                }
            }
        }
        __syncthreads();
    }
#pragma unroll
    for (int tt = 0; tt < TPB; ++tt) {
        int q = tid + tt * 256;
        if (q < NT) {
            int o4 = q % W4, t = (q / W4) % T, m4 = q / (W4 * T);
#pragma unroll
            for (int am = 0; am < 4; ++am) {
                float4 o;
                o.x = a[tt][am][0]; o.y = a[tt][am][1];
                o.z = a[tt][am][2]; o.w = a[tt][am][3];
                G4w[((m4 * 4 + am) * T + t) * W4 + o4] = o;
            }
        }
    }
    __syncthreads();

    for (int it = tid; it < MC * T * S4N; it += 256) {
        int s4 = it % S4N, t = (it / S4N) % T, mc = it / (S4N * T);
        float acc[4];
#pragma unroll
        for (int q = 0; q < 4; ++q)
            acc[q] = smem[OFF_G + (mc * T + t) * W + Jp + s4 * 4 + q];
        for (int j4 = 0; j4 < Jp / 4; ++j4) {
            int k = j4 / CQ, cinq = j4 % CQ;
            float4 g = G4[(mc * T + t) * W4 + j4];
#pragma unroll
            for (int q = 0; q < 4; ++q) {
                int s = s4 * 4 + q;
                int trow = s + k - 1;
                if (trow < 0) trow += T;
                if (trow >= T) trow -= T;
                float4 x4 = X2A4[(mc * T + trow) * CQ + cinq];
                acc[q] += g.x * x4.x + g.y * x4.y + g.z * x4.z + g.w * x4.w;
            }
        }
#pragma unroll
        for (int q = 0; q < 4; ++q)
            smem[OFF_S + (mc * T + t) * ST + s4 * 4 + q] = 0.0625f * acc[q];
    }
    __syncthreads();

    for (int rid = tid; rid < MC * T; rid += 256) {
        int base = OFF_S + rid * ST;
        float mx = -1e30f;
        for (int s = 0; s < T; ++s) mx = fmaxf(mx, smem[base + s]);
        float sum = 0.f;
        for (int s = 0; s < T; ++s) {
            float e = __expf(smem[base + s] - mx);
            smem[base + s] = e; sum += e;
        }
        float inv = 1.f / sum;
        for (int s = 0; s < T; ++s) smem[base + s] *= inv;
    }
    __syncthreads();

    float* accp = wsw + WS_ACC + c_accbase[c] * 128 + b * T * T;
    for (int e = tid; e < T * T; e += 256) {
        int t = e / T, s = e % T;
        float v = 0.f;
        for (int mc = 0; mc < vm; ++mc)
            v += smem[OFF_S + (mc * T + t) * ST + s];
        atomicAdd(&accp[e], v);
    }
}

// ---------------- Expand accumulated means to the full output ----------------
template<int P, int BR>
__device__ __forceinline__ void expand_body(const float* __restrict__ acc,
                                            float* __restrict__ outp) {
    constexpr int T = BR ? P : (L_ / P);
    for (int idx = threadIdx.x; idx < L_ * L_; idx += 256) {
        int r = idx / L_, c2 = idx % L_;
        int rt = BR ? (r % P) : (r / P);
        int ct = BR ? (c2 % P) : (c2 / P);
        outp[idx] = acc[rt * T + ct];
    }
}

__global__ __launch_bounds__(256) void expand_kernel(const float* __restrict__ ws,
                                                     float* __restrict__ out) {
    int c = blockIdx.x, b = blockIdx.y;
    int i = c / 6, br = (c % 6) / 3, l = c % 3;
    int p = 3 + 2 * i;
    int T = br ? p : (L_ / p);
    __shared__ float sAcc[1232];
    int abase = c_accbase[c] * 128 + b * T * T;
    for (int idx = threadIdx.x; idx < T * T; idx += 256)
        sAcc[idx] = ws[WS_ACC + abase + idx] * (1.f / (float)M_);
    __syncthreads();
    float* outp = out + ((size_t)(br * 9 + i * 3 + l) * B_ + (size_t)b) * (size_t)(L_ * L_);
    int key = i * 2 + br;
    switch (key) {
        case 0: expand_body<3, 0>(sAcc, outp); break;
        case 1: expand_body<3, 1>(sAcc, outp); break;
        case 2: expand_body<5, 0>(sAcc, outp); break;
        case 3: expand_body<5, 1>(sAcc, outp); break;
        case 4: expand_body<7, 0>(sAcc, outp); break;
        case 5: expand_body<7, 1>(sAcc, outp); break;
    }
}

extern "C" void kernel_launch(void* const* d_in, const int* in_sizes, int n_in,
                              void* d_out, int out_size, void* d_ws, size_t ws_size,
                              hipStream_t stream) {
    const float* x   = (const float*)d_in[0];
    const float* cp0 = (const float*)d_in[1];
    const float* cn0 = (const float*)d_in[2];
    const float* cp1 = (const float*)d_in[3];
    const float* cn1 = (const float*)d_in[4];
    const float* cp2 = (const float*)d_in[5];
    const float* cn2 = (const float*)d_in[6];
    const float* Wq  = (const float*)d_in[7];
    const float* bq  = (const float*)d_in[8];
    const float* Wk  = (const float*)d_in[9];
    const float* bk  = (const float*)d_in[10];
    float* ws = (float*)d_ws;
    float* out = (float*)d_out;

    const int use_partial = (ws_size >= WS_NEED_BYTES) ? 1 : 0;

    hipLaunchKernelGGL(revin_kernel, dim3(B_ * M_), dim3(128), 0, stream, x, ws);
    hipLaunchKernelGGL(pe_kernel, dim3(6), dim3(256), 0, stream, ws);
    if (use_partial) {
        hipLaunchKernelGGL(lr2_kernel, dim3(NCOMBO, 14, 4), dim3(256), 0, stream,
                           cp0, cn0, cp1, cn1, cp2, cn2, Wq, bq, Wk, bk, ws);
    } else {
        hipLaunchKernelGGL(lr_kernel, dim3(NCOMBO, 27), dim3(256), 0, stream,
                           cp0, cn0, cp1, cn1, cp2, cn2, Wq, bq, Wk, bk, ws);
    }
    hipLaunchKernelGGL(mm_kernel, dim3(NCOMBO, 49), dim3(256), 0, stream, ws, use_partial);
    hipLaunchKernelGGL(pack_kernel, dim3(NCOMBO), dim3(256), 0, stream, ws);
    hipLaunchKernelGGL(zero_acc, dim3((ACC_TOT / 4 + 255) / 256), dim3(256), 0, stream, ws);

    // BR=0: new attn3; BR=1: proven attn2
    hipLaunchKernelGGL((attn3<3>),    dim3(B_, 3, 14), dim3(256), 0, stream, ws, ws); // MC=4
    hipLaunchKernelGGL((attn2<3, 1>), dim3(B_, 3, 5),  dim3(256), 0, stream, ws, ws); // MC=12
    hipLaunchKernelGGL((attn3<5>),    dim3(B_, 3, 11), dim3(256), 0, stream, ws, ws); // MC=5
    hipLaunchKernelGGL((attn2<5, 1>), dim3(B_, 3, 7),  dim3(256), 0, stream, ws, ws); // MC=8
    hipLaunchKernelGGL((attn3<7>),    dim3(B_, 3, 7),  dim3(256), 0, stream, ws, ws); // MC=8
    hipLaunchKernelGGL((attn2<7, 1>), dim3(B_, 3, 7),  dim3(256), 0, stream, ws, ws); // MC=8

    hipLaunchKernelGGL(expand_kernel, dim3(NCOMBO, B_), dim3(256), 0, stream, ws, out);
}

// Round 10
// 497.400 us; speedup vs baseline: 2.2903x; 2.2903x over previous
//
#include <hip/hip_runtime.h>
#include <hip/hip_bf16.h>

// Problem constants
#define B_ 128
#define L_ 105
#define M_ 55
#define D_ 256
#define NCOMBO 18   // 3 patches x 2 branches x 3 layers

// Workspace layout (float offsets)
#define WS_XT    0          // normalized x^T: [B*M][105] = 739200
#define WS_PE    739200     // pos-embed tables: 86*256 = 22016
#define WS_LEFT  761216     // 18 * 27648 (fallback path; MP overlays after mm)
#define WS_RIGHT 1258880    // 18 * 27648 (ACC overlays after mm)
#define WS_MM    1756544    // 18 * 11664
#define WS_MP    761216     // 18 * 12544 (over LEFT, after mm)
#define WS_ACC   1258880    // 758016 floats (over RIGHT + MM tail)
#define LR_STRIDE 27648
#define MM_STRIDE 11664
#define MP_STRIDE 12544
#define ACC_TOT  758016

// K-split partial region (only used when ws_size is large enough)
#define WS_LRP        1966592
#define LRP_KZ_STRIDE 27648
#define LRP_C_STRIDE  110592
#define LRP_HALF      1990656
#define WS_NEED_BYTES ((size_t)(WS_LRP + 2 * LRP_HALF) * 4)

__constant__ int c_peOff[6] = {0, 35, 38, 59, 64, 79};
__constant__ int c_accbase[18] = {0,1225,2450, 3675,3684,3693, 3702,4143,4584,
                                  5025,5050,5075, 5100,5325,5550, 5775,5824,5873};

__device__ __forceinline__ void combo_dims(int c, int& i, int& br, int& l,
                                           int& p, int& n, int& Cin, int& T, int& J) {
    i = c / 6; br = (c % 6) / 3; l = c % 3;
    p = 3 + 2 * i;
    n = L_ / p;
    Cin = br ? n : p;
    T   = br ? p : n;
    J = 3 * Cin;
}

__device__ __forceinline__ float dot4(float4 a, float4 b) {
    return a.x * b.x + a.y * b.y + a.z * b.z + a.w * b.w;
}

// ---------------- RevIN normalize ----------------
__global__ void revin_kernel(const float* __restrict__ x, float* __restrict__ ws) {
    int bm = blockIdx.x; int b = bm / M_; int m = bm % M_;
    int tid = threadIdx.x;
    __shared__ float s1[128], s2[128];
    float v = 0.f;
    if (tid < L_) v = x[(b * L_ + tid) * M_ + m];
    s1[tid] = v; s2[tid] = v * v;
    __syncthreads();
    for (int off = 64; off > 0; off >>= 1) {
        if (tid < off) { s1[tid] += s1[tid + off]; s2[tid] += s2[tid + off]; }
        __syncthreads();
    }
    float mean = s1[0] * (1.f / L_);
    float var  = s2[0] * (1.f / L_) - mean * mean;
    float rstd = rsqrtf(var + 1e-5f);
    if (tid < L_) ws[WS_XT + bm * L_ + tid] = (v - mean) * rstd;
}

// ---------------- Positional embedding tables ----------------
__global__ void pe_kernel(float* __restrict__ ws) {
    int bi = blockIdx.x;
    int i = bi / 2, br = bi % 2;
    int p = 3 + 2 * i, n = L_ / p;
    int T = br ? p : n;
    int d = threadIdx.x;
    float divv = expf(-(float)(d & ~1) * (logf(10000.f) / (float)D_));
    float* base = ws + WS_PE + c_peOff[bi] * D_;
    for (int t = 0; t < T; ++t) {
        float arg = (float)t * divv;
        base[t * D_ + d] = (d & 1) ? cosf(arg) : sinf(arg);
    }
}

// ---------------- lr2: K-split x4, 8-row tiles, unique-writer partials ----------------
__global__ __launch_bounds__(256) void lr2_kernel(
                          const float* __restrict__ w0, const float* __restrict__ w1,
                          const float* __restrict__ w2c, const float* __restrict__ w3,
                          const float* __restrict__ w4, const float* __restrict__ w5,
                          const float* __restrict__ Wq, const float* __restrict__ bq,
                          const float* __restrict__ Wk, const float* __restrict__ bk,
                          float* __restrict__ ws) {
    int c = blockIdx.x;
    int i, br, l, p, n, Cin, T, J; combo_dims(c, i, br, l, p, n, Cin, T, J);
    int Mdim = J + T;
    int r0 = blockIdx.y * 8;
    if (r0 >= Mdim) return;
    int kz = blockIdx.z;
    int d0 = kz * 64;
    int wi = i * 2 + br;
    const float* conv = (wi == 0) ? w0 : (wi == 1) ? w1 : (wi == 2) ? w2c
                       : (wi == 3) ? w3 : (wi == 4) ? w4 : w5;
    __shared__ float S[8][64];
    int tid = threadIdx.x;
    for (int idx = tid; idx < 8 * 64; idx += 256) {
        int rr = idx >> 6, dd = idx & 63;
        int row = r0 + rr; float val = 0.f;
        int d = d0 + dd;
        if (row < J) val = conv[d * J + row];
        else if (row < Mdim) val = ws[WS_PE + (c_peOff[wi] + (row - J)) * D_ + d];
        S[rr][dd] = val;
    }
    __syncthreads();
    const float* wqp = Wq + l * D_ * D_;
    const float* wkp = Wk + l * D_ * D_;
    float accL[8], accR[8];
#pragma unroll
    for (int rr = 0; rr < 8; ++rr) { accL[rr] = 0.f; accR[rr] = 0.f; }
    int o = tid;
#pragma unroll 8
    for (int dd = 0; dd < 64; ++dd) {
        int d = d0 + dd;
        float wqv = wqp[d * D_ + o];
        float wkv = wkp[d * D_ + o];
#pragma unroll
        for (int rr = 0; rr < 8; ++rr) {
            float sv = S[rr][dd];
            accL[rr] += sv * wqv;
            accR[rr] += sv * wkv;
        }
    }
    float bqv = (kz == 0) ? bq[l * D_ + o] : 0.f;
    float bkv = (kz == 0) ? bk[l * D_ + o] : 0.f;
    float* Lp = ws + WS_LRP + c * LRP_C_STRIDE + kz * LRP_KZ_STRIDE;
    float* Rp = Lp + LRP_HALF;
#pragma unroll
    for (int rr = 0; rr < 8; ++rr) {
        int row = r0 + rr;
        if (row < Mdim) {
            float aq = (row >= J) ? bqv : 0.f;
            float ak = (row >= J) ? bkv : 0.f;
            Lp[row * D_ + o] = accL[rr] + aq;
            Rp[row * D_ + o] = accR[rr] + ak;
        }
    }
}

// ---------------- Fallback lr: 4 rows per block, full K ----------------
__global__ __launch_bounds__(256) void lr_kernel(
                          const float* __restrict__ w0, const float* __restrict__ w1,
                          const float* __restrict__ w2c, const float* __restrict__ w3,
                          const float* __restrict__ w4, const float* __restrict__ w5,
                          const float* __restrict__ Wq, const float* __restrict__ bq,
                          const float* __restrict__ Wk, const float* __restrict__ bk,
                          float* __restrict__ ws) {
    int c = blockIdx.x;
    int i, br, l, p, n, Cin, T, J; combo_dims(c, i, br, l, p, n, Cin, T, J);
    int Mdim = J + T;
    int r0 = blockIdx.y * 4;
    if (r0 >= Mdim) return;
    int wi = i * 2 + br;
    const float* conv = (wi == 0) ? w0 : (wi == 1) ? w1 : (wi == 2) ? w2c
                       : (wi == 3) ? w3 : (wi == 4) ? w4 : w5;
    __shared__ float S[4][256];
    int tid = threadIdx.x;
    for (int idx = tid; idx < 4 * 256; idx += 256) {
        int rr = idx >> 8, dd = idx & 255;
        int row = r0 + rr; float val = 0.f;
        if (row < J) val = conv[dd * J + row];
        else if (row < Mdim) val = ws[WS_PE + (c_peOff[wi] + (row - J)) * D_ + dd];
        S[rr][dd] = val;
    }
    __syncthreads();
    const float* wqp = Wq + l * D_ * D_;
    const float* wkp = Wk + l * D_ * D_;
    float accL[4], accR[4];
#pragma unroll
    for (int rr = 0; rr < 4; ++rr) { accL[rr] = 0.f; accR[rr] = 0.f; }
    int o = tid;
#pragma unroll 8
    for (int d = 0; d < D_; ++d) {
        float wqv = wqp[d * D_ + o];
        float wkv = wkp[d * D_ + o];
#pragma unroll
        for (int rr = 0; rr < 4; ++rr) {
            float sv = S[rr][d];
            accL[rr] += sv * wqv;
            accR[rr] += sv * wkv;
        }
    }
    float bqv = bq[l * D_ + o], bkv = bk[l * D_ + o];
#pragma unroll
    for (int rr = 0; rr < 4; ++rr) {
        int row = r0 + rr;
        if (row < Mdim) {
            float aq = (row >= J) ? bqv : 0.f;
            float ak = (row >= J) ? bkv : 0.f;
            ws[WS_LEFT  + c * LR_STRIDE + row * D_ + o] = accL[rr] + aq;
            ws[WS_RIGHT + c * LR_STRIDE + row * D_ + o] = accR[rr] + ak;
        }
    }
}

// ---------------- M' = Left @ Right^T (sums K-split partials when enabled) ------------
__global__ void mm_kernel(float* __restrict__ ws, int use_partial) {
    int c = blockIdx.x;
    int i, br, l, p, n, Cin, T, J; combo_dims(c, i, br, l, p, n, Cin, T, J);
    int Mdim = J + T;
    int tr = blockIdx.y / 7, tc = blockIdx.y % 7;
    int r0 = tr * 16, c0 = tc * 16;
    if (r0 >= Mdim || c0 >= Mdim) return;
    __shared__ __align__(16) float Lb[16][260], Rb[16][260];
    int tid = threadIdx.x;
    if (use_partial) {
        const float* Lp = ws + WS_LRP + c * LRP_C_STRIDE;
        const float* Rp = Lp + LRP_HALF;
        for (int idx = tid; idx < 16 * 256; idx += 256) {
            int rr = idx >> 8, d = idx & 255;
            int rL = r0 + rr, rR = c0 + rr;
            float lv = 0.f, rv = 0.f;
            if (rL < Mdim) {
                int base = rL * D_ + d;
                lv = Lp[base] + Lp[base + LRP_KZ_STRIDE]
                   + Lp[base + 2 * LRP_KZ_STRIDE] + Lp[base + 3 * LRP_KZ_STRIDE];
            }
            if (rR < Mdim) {
                int base = rR * D_ + d;
                rv = Rp[base] + Rp[base + LRP_KZ_STRIDE]
                   + Rp[base + 2 * LRP_KZ_STRIDE] + Rp[base + 3 * LRP_KZ_STRIDE];
            }
            Lb[rr][d] = lv; Rb[rr][d] = rv;
        }
    } else {
        for (int idx = tid; idx < 16 * 256; idx += 256) {
            int rr = idx >> 8, d = idx & 255;
            int rL = r0 + rr, rR = c0 + rr;
            Lb[rr][d] = (rL < Mdim) ? ws[WS_LEFT  + c * LR_STRIDE + rL * D_ + d] : 0.f;
            Rb[rr][d] = (rR < Mdim) ? ws[WS_RIGHT + c * LR_STRIDE + rR * D_ + d] : 0.f;
        }
    }
    __syncthreads();
    int rr = tid / 16, cc = tid % 16;
    const float4* lrow = (const float4*)(&Lb[rr][0]);
    const float4* rrow = (const float4*)(&Rb[cc][0]);
    float acc = 0.f;
#pragma unroll 8
    for (int d4 = 0; d4 < 64; ++d4) {
        float4 a = lrow[d4], bb = rrow[d4];
        acc += a.x * bb.x + a.y * bb.y + a.z * bb.z + a.w * bb.w;
    }
    int r = r0 + rr, cth = c0 + cc;
    if (r < Mdim && cth < Mdim)
        ws[WS_MM + c * MM_STRIDE + r * Mdim + cth] = acc;
}

// ---------------- Pack M' into reordered/padded Mp [W x W] per combo ----------------
__global__ void pack_kernel(float* __restrict__ ws) {
    int c = blockIdx.x;
    int i, br, l, p, n, Cin, T, J; combo_dims(c, i, br, l, p, n, Cin, T, J);
    int Mdim = J + T;
    int Cinp = (Cin + 3) & ~3;
    int Jp = 3 * Cinp;
    int T4 = (T + 3) & ~3;
    int W = Jp + T4;
    const float* MMc = ws + WS_MM + c * MM_STRIDE;
    float* Mp = ws + WS_MP + c * MP_STRIDE;
    for (int e = threadIdx.x; e < W * W; e += 256) {
        int r = e / W, o = e % W;
        int srcr = -1, srcc = -1;
        bool brow = false;
        if (r < Jp) {
            int k = r / Cinp, cin = r % Cinp;
            if (cin < Cin) srcr = cin * 3 + k;
        } else {
            int t = r - Jp;
            if (t < T) { srcr = J + t; brow = true; }
        }
        if (o < Jp) {
            int k2 = o / Cinp, cin2 = o % Cinp;
            if (cin2 < Cin) srcc = cin2 * 3 + k2;
        } else {
            int s = o - Jp;
            if (s < T) srcc = J + s;
        }
        float val;
        if (srcr >= 0 && srcc >= 0) val = MMc[srcr * Mdim + srcc];
        else if (brow && o >= Jp && srcc < 0) val = -1e30f;  // padded-s bias: kill in softmax
        else val = 0.f;
        Mp[e] = val;
    }
}

// ---------------- Zero the atomic accumulator region ----------------
__global__ void zero_acc(float* __restrict__ ws) {
    int idx = blockIdx.x * 256 + threadIdx.x;
    if (idx < ACC_TOT / 4) {
        float4 z; z.x = 0.f; z.y = 0.f; z.z = 0.f; z.w = 0.f;
        ((float4*)(ws + WS_ACC))[idx] = z;
    }
}

// ---------------- Fused attention (r8 structure; BR=0 gets t-tiled S + reg softmax) ----
template<int P, int BR>
__global__ __launch_bounds__(256) void attn2(const float* __restrict__ ws,
                                             float* __restrict__ wsw) {
    constexpr int N    = L_ / P;
    constexpr int Cin  = BR ? N : P;
    constexpr int T    = BR ? P : N;
    constexpr int Cinp = (Cin + 3) & ~3;
    constexpr int Jp   = 3 * Cinp;
    constexpr int T4   = (T + 3) & ~3;
    constexpr int W    = Jp + T4;
    constexpr int W4   = W / 4;
    constexpr int ST   = T4 + 1;
    constexpr int II   = (P - 3) / 2;
    constexpr int MC   = BR ? (P == 3 ? 12 : 8) : (P == 7 ? 8 : 4);
    constexpr int GT   = BR ? T : T4;            // G rows padded to T4 for BR=0 t-tiling
    constexpr int TT   = (BR == 0) ? (P == 3 ? 4 : 2) : 1;  // t-tile height (BR=0)
    constexpr int NT   = (MC / 4) * T * W4;
    constexpr int TPB  = (NT + 255) / 256;
    constexpr int MCQ  = MC / 4;
    constexpr int CQ   = Cinp / 4;
    constexpr int S4N  = T4 / 4;
    constexpr int OFF_X2T = 0;
    constexpr int OFF_X2A = OFF_X2T + T * Cinp * MC;
    constexpr int OFF_MSL = OFF_X2A + T * Cinp * MC;
    constexpr int OFF_G   = OFF_MSL + Cinp * W;
    constexpr int OFF_S   = OFF_G + MC * GT * W;
    constexpr int TOT     = OFF_S + MC * T * ST;
    static_assert(TOT * 4 <= 65536, "LDS budget");

    __shared__ __align__(16) float smem[TOT];
    const int tid = threadIdx.x;
    const int b = blockIdx.x, l = blockIdx.y, sp = blockIdx.z;
    const int c = II * 6 + BR * 3 + l;
    const int m0 = sp * MC;
    const int vm = (M_ - m0 < MC) ? (M_ - m0) : MC;

    const float*  Mpg  = ws + WS_MP + c * MP_STRIDE;
    const float4* Mpg4 = (const float4*)Mpg;

    for (int e = tid; e < T * Cinp * MC; e += 256) {
        int mcol = e % MC, rest = e / MC;
        int cin = rest % Cinp, trow = rest / Cinp;
        float v = 0.f;
        if (cin < Cin && m0 + mcol < M_)
            v = ws[WS_XT + (size_t)(b * M_ + m0 + mcol) * L_ + trow * Cin + cin];
        smem[OFF_X2T + e] = v;
    }
    for (int e = tid; e < T * Cinp * MC; e += 256) {
        int cin = e % Cinp, trow = (e / Cinp) % T, mcol = e / (Cinp * T);
        float v = 0.f;
        if (cin < Cin && m0 + mcol < M_)
            v = ws[WS_XT + (size_t)(b * M_ + m0 + mcol) * L_ + trow * Cin + cin];
        smem[OFF_X2A + e] = v;
    }

    const float4* X2T4 = (const float4*)(smem + OFF_X2T);
    const float4* X2A4 = (const float4*)(smem + OFF_X2A);
    float4*       MSL4 = (float4*)(smem + OFF_MSL);
    float4*       G4w  = (float4*)(smem + OFF_G);
    const float4* G4   = (const float4*)(smem + OFF_G);

    // ---- G-phase: register-tiled GEMM, bias init, 3 k-slices of Mp ----
    float a[TPB][4][4];
#pragma unroll
    for (int tt = 0; tt < TPB; ++tt) {
        int q = tid + tt * 256;
        if (q < NT) {
            int o4 = q % W4, t = (q / W4) % T;
            float4 bv = Mpg4[(Jp + t) * W4 + o4];
#pragma unroll
            for (int am = 0; am < 4; ++am) {
                a[tt][am][0] = bv.x; a[tt][am][1] = bv.y;
                a[tt][am][2] = bv.z; a[tt][am][3] = bv.w;
            }
        }
    }
    __syncthreads();
    for (int k = 0; k < 3; ++k) {
        for (int e = tid; e < Cinp * W4; e += 256)
            MSL4[e] = Mpg4[k * Cinp * W4 + e];
        __syncthreads();
#pragma unroll
        for (int tt = 0; tt < TPB; ++tt) {
            int q = tid + tt * 256;
            if (q < NT) {
                int o4 = q % W4, t = (q / W4) % T, m4 = q / (W4 * T);
                int trow = t + k - 1;
                if (trow < 0) trow += T;
                if (trow >= T) trow -= T;
                const float4* xp = X2T4 + trow * Cinp * MCQ + m4;
                const float4* mp = MSL4 + o4;
#pragma unroll 4
                for (int cin = 0; cin < Cinp; ++cin) {
                    float4 x4 = xp[cin * MCQ];
                    float4 mv = mp[cin * W4];
#pragma unroll
                    for (int aq = 0; aq < 4; ++aq) {
                        float m = (aq == 0) ? mv.x : (aq == 1) ? mv.y : (aq == 2) ? mv.z : mv.w;
                        a[tt][0][aq] += x4.x * m;
                        a[tt][1][aq] += x4.y * m;
                        a[tt][2][aq] += x4.z * m;
                        a[tt][3][aq] += x4.w * m;
                    }
                }
            }
        }
        __syncthreads();
    }
#pragma unroll
    for (int tt = 0; tt < TPB; ++tt) {
        int q = tid + tt * 256;
        if (q < NT) {
            int o4 = q % W4, t = (q / W4) % T, m4 = q / (W4 * T);
#pragma unroll
            for (int am = 0; am < 4; ++am) {
                float4 o;
                o.x = a[tt][am][0]; o.y = a[tt][am][1];
                o.z = a[tt][am][2]; o.w = a[tt][am][3];
                G4w[((m4 * 4 + am) * GT + t) * W4 + o4] = o;
            }
        }
    }
    __syncthreads();

    if constexpr (BR == 0) {
        // ---- S-phase: TTx4s register tile over padded G rows ----
        constexpr int TQ = T4 / TT;
        for (int it = tid; it < MC * TQ * S4N; it += 256) {
            int s4 = it % S4N, tq = (it / S4N) % TQ, mc = it / (S4N * TQ);
            float acc[TT][4];
#pragma unroll
            for (int at = 0; at < TT; ++at) {
                int t = tq * TT + at;
#pragma unroll
                for (int q = 0; q < 4; ++q)
                    acc[at][q] = smem[OFF_G + (mc * GT + t) * W + Jp + s4 * 4 + q];
            }
#pragma unroll
            for (int j4 = 0; j4 < Jp / 4; ++j4) {
                int k = j4 / CQ, cinq = j4 % CQ;
                float4 g[TT];
#pragma unroll
                for (int at = 0; at < TT; ++at)
                    g[at] = G4[(mc * GT + tq * TT + at) * W4 + j4];
#pragma unroll
                for (int q = 0; q < 4; ++q) {
                    int s = s4 * 4 + q;
                    int trow = s + k - 1;
                    if (trow < 0) trow += T;
                    if (trow >= T) trow -= T;
                    float4 x4 = X2A4[(mc * T + trow) * CQ + cinq];
#pragma unroll
                    for (int at = 0; at < TT; ++at)
                        acc[at][q] += dot4(g[at], x4);
                }
            }
#pragma unroll
            for (int at = 0; at < TT; ++at) {
                int t = tq * TT + at;
                if (t < T) {
#pragma unroll
                    for (int q = 0; q < 4; ++q)
                        smem[OFF_S + (mc * T + t) * ST + s4 * 4 + q] = 0.0625f * acc[at][q];
                }
            }
        }
        __syncthreads();
        // ---- single-pass register softmax (pads carry huge negatives -> exp 0) ----
        for (int rid = tid; rid < MC * T; rid += 256) {
            int base = OFF_S + rid * ST;
            float pr[T4];
#pragma unroll
            for (int s = 0; s < T4; ++s) pr[s] = smem[base + s];
            float mx = -1e30f;
#pragma unroll
            for (int s = 0; s < T4; ++s) mx = fmaxf(mx, pr[s]);
            float sum = 0.f;
#pragma unroll
            for (int s = 0; s < T4; ++s) { pr[s] = __expf(pr[s] - mx); sum += pr[s]; }
            float inv = 1.f / sum;
#pragma unroll
            for (int s = 0; s < T; ++s) smem[base + s] = pr[s] * inv;
        }
        __syncthreads();
    } else {
        // ---- r8-proven BR=1 S-phase + scalar softmax ----
        for (int it = tid; it < MC * T * S4N; it += 256) {
            int s4 = it % S4N, t = (it / S4N) % T, mc = it / (S4N * T);
            float acc[4];
#pragma unroll
            for (int q = 0; q < 4; ++q)
                acc[q] = smem[OFF_G + (mc * T + t) * W + Jp + s4 * 4 + q];
            for (int j4 = 0; j4 < Jp / 4; ++j4) {
                int k = j4 / CQ, cinq = j4 % CQ;
                float4 g = G4[(mc * T + t) * W4 + j4];
#pragma unroll
                for (int q = 0; q < 4; ++q) {
                    int s = s4 * 4 + q;
                    int trow = s + k - 1;
                    if (trow < 0) trow += T;
                    if (trow >= T) trow -= T;
                    float4 x4 = X2A4[(mc * T + trow) * CQ + cinq];
                    acc[q] += g.x * x4.x + g.y * x4.y + g.z * x4.z + g.w * x4.w;
                }
            }
#pragma unroll
            for (int q = 0; q < 4; ++q)
                smem[OFF_S + (mc * T + t) * ST + s4 * 4 + q] = 0.0625f * acc[q];
        }
        __syncthreads();
        for (int rid = tid; rid < MC * T; rid += 256) {
            int base = OFF_S + rid * ST;
            float mx = -1e30f;
            for (int s = 0; s < T; ++s) mx = fmaxf(mx, smem[base + s]);
            float sum = 0.f;
            for (int s = 0; s < T; ++s) {
                float e = __expf(smem[base + s] - mx);
                smem[base + s] = e; sum += e;
            }
            float inv = 1.f / sum;
            for (int s = 0; s < T; ++s) smem[base + s] *= inv;
        }
        __syncthreads();
    }

    float* accp = wsw + WS_ACC + c_accbase[c] * 128 + b * T * T;
    for (int e = tid; e < T * T; e += 256) {
        int t = e / T, s = e % T;
        float v = 0.f;
        for (int mc = 0; mc < vm; ++mc)
            v += smem[OFF_S + (mc * T + t) * ST + s];
        atomicAdd(&accp[e], v);
    }
}

// ---------------- Expand accumulated means to the full output ----------------
template<int P, int BR>
__device__ __forceinline__ void expand_body(const float* __restrict__ acc,
                                            float* __restrict__ outp) {
    constexpr int T = BR ? P : (L_ / P);
    for (int idx = threadIdx.x; idx < L_ * L_; idx += 256) {
        int r = idx / L_, c2 = idx % L_;
        int rt = BR ? (r % P) : (r / P);
        int ct = BR ? (c2 % P) : (c2 / P);
        outp[idx] = acc[rt * T + ct];
    }
}

__global__ __launch_bounds__(256) void expand_kernel(const float* __restrict__ ws,
                                                     float* __restrict__ out) {
    int c = blockIdx.x, b = blockIdx.y;
    int i = c / 6, br = (c % 6) / 3, l = c % 3;
    int p = 3 + 2 * i;
    int T = br ? p : (L_ / p);
    __shared__ float sAcc[1232];
    int abase = c_accbase[c] * 128 + b * T * T;
    for (int idx = threadIdx.x; idx < T * T; idx += 256)
        sAcc[idx] = ws[WS_ACC + abase + idx] * (1.f / (float)M_);
    __syncthreads();
    float* outp = out + ((size_t)(br * 9 + i * 3 + l) * B_ + (size_t)b) * (size_t)(L_ * L_);
    int key = i * 2 + br;
    switch (key) {
        case 0: expand_body<3, 0>(sAcc, outp); break;
        case 1: expand_body<3, 1>(sAcc, outp); break;
        case 2: expand_body<5, 0>(sAcc, outp); break;
        case 3: expand_body<5, 1>(sAcc, outp); break;
        case 4: expand_body<7, 0>(sAcc, outp); break;
        case 5: expand_body<7, 1>(sAcc, outp); break;
    }
}

extern "C" void kernel_launch(void* const* d_in, const int* in_sizes, int n_in,
                              void* d_out, int out_size, void* d_ws, size_t ws_size,
                              hipStream_t stream) {
    const float* x   = (const float*)d_in[0];
    const float* cp0 = (const float*)d_in[1];
    const float* cn0 = (const float*)d_in[2];
    const float* cp1 = (const float*)d_in[3];
    const float* cn1 = (const float*)d_in[4];
    const float* cp2 = (const float*)d_in[5];
    const float* cn2 = (const float*)d_in[6];
    const float* Wq  = (const float*)d_in[7];
    const float* bq  = (const float*)d_in[8];
    const float* Wk  = (const float*)d_in[9];
    const float* bk  = (const float*)d_in[10];
    float* ws = (float*)d_ws;
    float* out = (float*)d_out;

    const int use_partial = (ws_size >= WS_NEED_BYTES) ? 1 : 0;

    hipLaunchKernelGGL(revin_kernel, dim3(B_ * M_), dim3(128), 0, stream, x, ws);
    hipLaunchKernelGGL(pe_kernel, dim3(6), dim3(256), 0, stream, ws);
    if (use_partial) {
        hipLaunchKernelGGL(lr2_kernel, dim3(NCOMBO, 14, 4), dim3(256), 0, stream,
                           cp0, cn0, cp1, cn1, cp2, cn2, Wq, bq, Wk, bk, ws);
    } else {
        hipLaunchKernelGGL(lr_kernel, dim3(NCOMBO, 27), dim3(256), 0, stream,
                           cp0, cn0, cp1, cn1, cp2, cn2, Wq, bq, Wk, bk, ws);
    }
    hipLaunchKernelGGL(mm_kernel, dim3(NCOMBO, 49), dim3(256), 0, stream, ws, use_partial);
    hipLaunchKernelGGL(pack_kernel, dim3(NCOMBO), dim3(256), 0, stream, ws);
    hipLaunchKernelGGL(zero_acc, dim3((ACC_TOT / 4 + 255) / 256), dim3(256), 0, stream, ws);

    hipLaunchKernelGGL((attn2<3, 0>), dim3(B_, 3, 14), dim3(256), 0, stream, ws, ws); // MC=4
    hipLaunchKernelGGL((attn2<3, 1>), dim3(B_, 3, 5),  dim3(256), 0, stream, ws, ws); // MC=12
    hipLaunchKernelGGL((attn2<5, 0>), dim3(B_, 3, 14), dim3(256), 0, stream, ws, ws); // MC=4
    hipLaunchKernelGGL((attn2<5, 1>), dim3(B_, 3, 7),  dim3(256), 0, stream, ws, ws); // MC=8
    hipLaunchKernelGGL((attn2<7, 0>), dim3(B_, 3, 7),  dim3(256), 0, stream, ws, ws); // MC=8
    hipLaunchKernelGGL((attn2<7, 1>), dim3(B_, 3, 7),  dim3(256), 0, stream, ws, ws); // MC=8

    hipLaunchKernelGGL(expand_kernel, dim3(NCOMBO, B_), dim3(256), 0, stream, ws, out);
}

// Round 11
// 484.113 us; speedup vs baseline: 2.3532x; 1.0274x over previous
//
#include <hip/hip_runtime.h>
#include <hip/hip_bf16.h>

// Problem constants
#define B_ 128
#define L_ 105
#define M_ 55
#define D_ 256
#define NCOMBO 18   // 3 patches x 2 branches x 3 layers

// Workspace layout (float offsets)
#define WS_XT    0          // normalized x^T: [B*M][105] = 739200
#define WS_PE    739200     // pos-embed tables: 86*256 = 22016
#define WS_LEFT  761216     // 18 * 27648 (fallback path; MP overlays after mm)
#define WS_RIGHT 1258880    // 18 * 27648 (ACC overlays after mm)
#define WS_MM    1756544    // 18 * 11664
#define WS_MP    761216     // 18 * 12544 (over LEFT, after mm)
#define WS_ACC   1258880    // 758016 floats (over RIGHT + MM tail)
#define LR_STRIDE 27648
#define MM_STRIDE 11664
#define MP_STRIDE 12544
#define ACC_TOT  758016

// K-split partial region (only used when ws_size is large enough)
#define WS_LRP        1966592
#define LRP_KZ_STRIDE 27648
#define LRP_C_STRIDE  110592
#define LRP_HALF      1990656
#define WS_NEED_BYTES ((size_t)(WS_LRP + 2 * LRP_HALF) * 4)

__constant__ int c_peOff[6] = {0, 35, 38, 59, 64, 79};
__constant__ int c_accbase[18] = {0,1225,2450, 3675,3684,3693, 3702,4143,4584,
                                  5025,5050,5075, 5100,5325,5550, 5775,5824,5873};

__device__ __forceinline__ void combo_dims(int c, int& i, int& br, int& l,
                                           int& p, int& n, int& Cin, int& T, int& J) {
    i = c / 6; br = (c % 6) / 3; l = c % 3;
    p = 3 + 2 * i;
    n = L_ / p;
    Cin = br ? n : p;
    T   = br ? p : n;
    J = 3 * Cin;
}

__device__ __forceinline__ float dot4(float4 a, float4 b) {
    return a.x * b.x + a.y * b.y + a.z * b.z + a.w * b.w;
}

// ---------------- RevIN normalize ----------------
__global__ void revin_kernel(const float* __restrict__ x, float* __restrict__ ws) {
    int bm = blockIdx.x; int b = bm / M_; int m = bm % M_;
    int tid = threadIdx.x;
    __shared__ float s1[128], s2[128];
    float v = 0.f;
    if (tid < L_) v = x[(b * L_ + tid) * M_ + m];
    s1[tid] = v; s2[tid] = v * v;
    __syncthreads();
    for (int off = 64; off > 0; off >>= 1) {
        if (tid < off) { s1[tid] += s1[tid + off]; s2[tid] += s2[tid + off]; }
        __syncthreads();
    }
    float mean = s1[0] * (1.f / L_);
    float var  = s2[0] * (1.f / L_) - mean * mean;
    float rstd = rsqrtf(var + 1e-5f);
    if (tid < L_) ws[WS_XT + bm * L_ + tid] = (v - mean) * rstd;
}

// ---------------- Positional embedding tables ----------------
__global__ void pe_kernel(float* __restrict__ ws) {
    int bi = blockIdx.x;
    int i = bi / 2, br = bi % 2;
    int p = 3 + 2 * i, n = L_ / p;
    int T = br ? p : n;
    int d = threadIdx.x;
    float divv = expf(-(float)(d & ~1) * (logf(10000.f) / (float)D_));
    float* base = ws + WS_PE + c_peOff[bi] * D_;
    for (int t = 0; t < T; ++t) {
        float arg = (float)t * divv;
        base[t * D_ + d] = (d & 1) ? cosf(arg) : sinf(arg);
    }
}

// ---------------- lr2: K-split x4, 8-row tiles, unique-writer partials ----------------
__global__ __launch_bounds__(256) void lr2_kernel(
                          const float* __restrict__ w0, const float* __restrict__ w1,
                          const float* __restrict__ w2c, const float* __restrict__ w3,
                          const float* __restrict__ w4, const float* __restrict__ w5,
                          const float* __restrict__ Wq, const float* __restrict__ bq,
                          const float* __restrict__ Wk, const float* __restrict__ bk,
                          float* __restrict__ ws) {
    int c = blockIdx.x;
    int i, br, l, p, n, Cin, T, J; combo_dims(c, i, br, l, p, n, Cin, T, J);
    int Mdim = J + T;
    int r0 = blockIdx.y * 8;
    if (r0 >= Mdim) return;
    int kz = blockIdx.z;
    int d0 = kz * 64;
    int wi = i * 2 + br;
    const float* conv = (wi == 0) ? w0 : (wi == 1) ? w1 : (wi == 2) ? w2c
                       : (wi == 3) ? w3 : (wi == 4) ? w4 : w5;
    __shared__ float S[8][64];
    int tid = threadIdx.x;
    for (int idx = tid; idx < 8 * 64; idx += 256) {
        int rr = idx >> 6, dd = idx & 63;
        int row = r0 + rr; float val = 0.f;
        int d = d0 + dd;
        if (row < J) val = conv[d * J + row];
        else if (row < Mdim) val = ws[WS_PE + (c_peOff[wi] + (row - J)) * D_ + d];
        S[rr][dd] = val;
    }
    __syncthreads();
    const float* wqp = Wq + l * D_ * D_;
    const float* wkp = Wk + l * D_ * D_;
    float accL[8], accR[8];
#pragma unroll
    for (int rr = 0; rr < 8; ++rr) { accL[rr] = 0.f; accR[rr] = 0.f; }
    int o = tid;
#pragma unroll 8
    for (int dd = 0; dd < 64; ++dd) {
        int d = d0 + dd;
        float wqv = wqp[d * D_ + o];
        float wkv = wkp[d * D_ + o];
#pragma unroll
        for (int rr = 0; rr < 8; ++rr) {
            float sv = S[rr][dd];
            accL[rr] += sv * wqv;
            accR[rr] += sv * wkv;
        }
    }
    float bqv = (kz == 0) ? bq[l * D_ + o] : 0.f;
    float bkv = (kz == 0) ? bk[l * D_ + o] : 0.f;
    float* Lp = ws + WS_LRP + c * LRP_C_STRIDE + kz * LRP_KZ_STRIDE;
    float* Rp = Lp + LRP_HALF;
#pragma unroll
    for (int rr = 0; rr < 8; ++rr) {
        int row = r0 + rr;
        if (row < Mdim) {
            float aq = (row >= J) ? bqv : 0.f;
            float ak = (row >= J) ? bkv : 0.f;
            Lp[row * D_ + o] = accL[rr] + aq;
            Rp[row * D_ + o] = accR[rr] + ak;
        }
    }
}

// ---------------- Fallback lr: 4 rows per block, full K ----------------
__global__ __launch_bounds__(256) void lr_kernel(
                          const float* __restrict__ w0, const float* __restrict__ w1,
                          const float* __restrict__ w2c, const float* __restrict__ w3,
                          const float* __restrict__ w4, const float* __restrict__ w5,
                          const float* __restrict__ Wq, const float* __restrict__ bq,
                          const float* __restrict__ Wk, const float* __restrict__ bk,
                          float* __restrict__ ws) {
    int c = blockIdx.x;
    int i, br, l, p, n, Cin, T, J; combo_dims(c, i, br, l, p, n, Cin, T, J);
    int Mdim = J + T;
    int r0 = blockIdx.y * 4;
    if (r0 >= Mdim) return;
    int wi = i * 2 + br;
    const float* conv = (wi == 0) ? w0 : (wi == 1) ? w1 : (wi == 2) ? w2c
                       : (wi == 3) ? w3 : (wi == 4) ? w4 : w5;
    __shared__ float S[4][256];
    int tid = threadIdx.x;
    for (int idx = tid; idx < 4 * 256; idx += 256) {
        int rr = idx >> 8, dd = idx & 255;
        int row = r0 + rr; float val = 0.f;
        if (row < J) val = conv[dd * J + row];
        else if (row < Mdim) val = ws[WS_PE + (c_peOff[wi] + (row - J)) * D_ + dd];
        S[rr][dd] = val;
    }
    __syncthreads();
    const float* wqp = Wq + l * D_ * D_;
    const float* wkp = Wk + l * D_ * D_;
    float accL[4], accR[4];
#pragma unroll
    for (int rr = 0; rr < 4; ++rr) { accL[rr] = 0.f; accR[rr] = 0.f; }
    int o = tid;
#pragma unroll 8
    for (int d = 0; d < D_; ++d) {
        float wqv = wqp[d * D_ + o];
        float wkv = wkp[d * D_ + o];
#pragma unroll
        for (int rr = 0; rr < 4; ++rr) {
            float sv = S[rr][d];
            accL[rr] += sv * wqv;
            accR[rr] += sv * wkv;
        }
    }
    float bqv = bq[l * D_ + o], bkv = bk[l * D_ + o];
#pragma unroll
    for (int rr = 0; rr < 4; ++rr) {
        int row = r0 + rr;
        if (row < Mdim) {
            float aq = (row >= J) ? bqv : 0.f;
            float ak = (row >= J) ? bkv : 0.f;
            ws[WS_LEFT  + c * LR_STRIDE + row * D_ + o] = accL[rr] + aq;
            ws[WS_RIGHT + c * LR_STRIDE + row * D_ + o] = accR[rr] + ak;
        }
    }
}

// ---------------- M' = Left @ Right^T (sums K-split partials when enabled) ------------
__global__ void mm_kernel(float* __restrict__ ws, int use_partial) {
    int c = blockIdx.x;
    int i, br, l, p, n, Cin, T, J; combo_dims(c, i, br, l, p, n, Cin, T, J);
    int Mdim = J + T;
    int tr = blockIdx.y / 7, tc = blockIdx.y % 7;
    int r0 = tr * 16, c0 = tc * 16;
    if (r0 >= Mdim || c0 >= Mdim) return;
    __shared__ __align__(16) float Lb[16][260], Rb[16][260];
    int tid = threadIdx.x;
    if (use_partial) {
        const float* Lp = ws + WS_LRP + c * LRP_C_STRIDE;
        const float* Rp = Lp + LRP_HALF;
        for (int idx = tid; idx < 16 * 256; idx += 256) {
            int rr = idx >> 8, d = idx & 255;
            int rL = r0 + rr, rR = c0 + rr;
            float lv = 0.f, rv = 0.f;
            if (rL < Mdim) {
                int base = rL * D_ + d;
                lv = Lp[base] + Lp[base + LRP_KZ_STRIDE]
                   + Lp[base + 2 * LRP_KZ_STRIDE] + Lp[base + 3 * LRP_KZ_STRIDE];
            }
            if (rR < Mdim) {
                int base = rR * D_ + d;
                rv = Rp[base] + Rp[base + LRP_KZ_STRIDE]
                   + Rp[base + 2 * LRP_KZ_STRIDE] + Rp[base + 3 * LRP_KZ_STRIDE];
            }
            Lb[rr][d] = lv; Rb[rr][d] = rv;
        }
    } else {
        for (int idx = tid; idx < 16 * 256; idx += 256) {
            int rr = idx >> 8, d = idx & 255;
            int rL = r0 + rr, rR = c0 + rr;
            Lb[rr][d] = (rL < Mdim) ? ws[WS_LEFT  + c * LR_STRIDE + rL * D_ + d] : 0.f;
            Rb[rr][d] = (rR < Mdim) ? ws[WS_RIGHT + c * LR_STRIDE + rR * D_ + d] : 0.f;
        }
    }
    __syncthreads();
    int rr = tid / 16, cc = tid % 16;
    const float4* lrow = (const float4*)(&Lb[rr][0]);
    const float4* rrow = (const float4*)(&Rb[cc][0]);
    float acc = 0.f;
#pragma unroll 8
    for (int d4 = 0; d4 < 64; ++d4) {
        float4 a = lrow[d4], bb = rrow[d4];
        acc += a.x * bb.x + a.y * bb.y + a.z * bb.z + a.w * bb.w;
    }
    int r = r0 + rr, cth = c0 + cc;
    if (r < Mdim && cth < Mdim)
        ws[WS_MM + c * MM_STRIDE + r * Mdim + cth] = acc;
}

// ---------------- Pack M' into reordered/padded Mp [W x W] per combo ----------------
__global__ void pack_kernel(float* __restrict__ ws) {
    int c = blockIdx.x;
    int i, br, l, p, n, Cin, T, J; combo_dims(c, i, br, l, p, n, Cin, T, J);
    int Mdim = J + T;
    int Cinp = (Cin + 3) & ~3;
    int Jp = 3 * Cinp;
    int T4 = (T + 3) & ~3;
    int W = Jp + T4;
    const float* MMc = ws + WS_MM + c * MM_STRIDE;
    float* Mp = ws + WS_MP + c * MP_STRIDE;
    for (int e = threadIdx.x; e < W * W; e += 256) {
        int r = e / W, o = e % W;
        int srcr = -1, srcc = -1;
        bool brow = false;
        if (r < Jp) {
            int k = r / Cinp, cin = r % Cinp;
            if (cin < Cin) srcr = cin * 3 + k;
        } else {
            int t = r - Jp;
            if (t < T) { srcr = J + t; brow = true; }
        }
        if (o < Jp) {
            int k2 = o / Cinp, cin2 = o % Cinp;
            if (cin2 < Cin) srcc = cin2 * 3 + k2;
        } else {
            int s = o - Jp;
            if (s < T) srcc = J + s;
        }
        float val;
        if (srcr >= 0 && srcc >= 0) val = MMc[srcr * Mdim + srcc];
        else if (brow && o >= Jp && srcc < 0) val = -1e30f;  // padded-s bias: kill in softmax
        else val = 0.f;
        Mp[e] = val;
    }
}

// ---------------- Zero the atomic accumulator region ----------------
__global__ void zero_acc(float* __restrict__ ws) {
    int idx = blockIdx.x * 256 + threadIdx.x;
    if (idx < ACC_TOT / 4) {
        float4 z; z.x = 0.f; z.y = 0.f; z.z = 0.f; z.w = 0.f;
        ((float4*)(ws + WS_ACC))[idx] = z;
    }
}

// ---------------- Fused attention (r8 S-phase + register single-pass softmax) ----------
template<int P, int BR>
__global__ __launch_bounds__(256) void attn2(const float* __restrict__ ws,
                                             float* __restrict__ wsw) {
    constexpr int N    = L_ / P;
    constexpr int Cin  = BR ? N : P;
    constexpr int T    = BR ? P : N;
    constexpr int Cinp = (Cin + 3) & ~3;
    constexpr int Jp   = 3 * Cinp;
    constexpr int T4   = (T + 3) & ~3;
    constexpr int W    = Jp + T4;
    constexpr int W4   = W / 4;
    constexpr int ST   = T4 + 1;
    constexpr int II   = (P - 3) / 2;
    constexpr int MC   = BR ? (P == 3 ? 12 : 8) : (P == 7 ? 8 : 4);
    constexpr int NT   = (MC / 4) * T * W4;
    constexpr int TPB  = (NT + 255) / 256;
    constexpr int MCQ  = MC / 4;
    constexpr int CQ   = Cinp / 4;
    constexpr int S4N  = T4 / 4;
    constexpr int OFF_X2T = 0;
    constexpr int OFF_X2A = OFF_X2T + T * Cinp * MC;
    constexpr int OFF_MSL = OFF_X2A + T * Cinp * MC;
    constexpr int OFF_G   = OFF_MSL + Cinp * W;
    constexpr int OFF_S   = OFF_G + MC * T * W;
    constexpr int TOT     = OFF_S + MC * T * ST;
    static_assert(TOT * 4 <= 65536, "LDS budget");

    __shared__ __align__(16) float smem[TOT];
    const int tid = threadIdx.x;
    const int b = blockIdx.x, l = blockIdx.y, sp = blockIdx.z;
    const int c = II * 6 + BR * 3 + l;
    const int m0 = sp * MC;
    const int vm = (M_ - m0 < MC) ? (M_ - m0) : MC;

    const float*  Mpg  = ws + WS_MP + c * MP_STRIDE;
    const float4* Mpg4 = (const float4*)Mpg;

    for (int e = tid; e < T * Cinp * MC; e += 256) {
        int mcol = e % MC, rest = e / MC;
        int cin = rest % Cinp, trow = rest / Cinp;
        float v = 0.f;
        if (cin < Cin && m0 + mcol < M_)
            v = ws[WS_XT + (size_t)(b * M_ + m0 + mcol) * L_ + trow * Cin + cin];
        smem[OFF_X2T + e] = v;
    }
    for (int e = tid; e < T * Cinp * MC; e += 256) {
        int cin = e % Cinp, trow = (e / Cinp) % T, mcol = e / (Cinp * T);
        float v = 0.f;
        if (cin < Cin && m0 + mcol < M_)
            v = ws[WS_XT + (size_t)(b * M_ + m0 + mcol) * L_ + trow * Cin + cin];
        smem[OFF_X2A + e] = v;
    }

    const float4* X2T4 = (const float4*)(smem + OFF_X2T);
    const float4* X2A4 = (const float4*)(smem + OFF_X2A);
    float4*       MSL4 = (float4*)(smem + OFF_MSL);
    float4*       G4w  = (float4*)(smem + OFF_G);
    const float4* G4   = (const float4*)(smem + OFF_G);

    // ---- G-phase: register-tiled GEMM, bias init, 3 k-slices of Mp ----
    float a[TPB][4][4];
#pragma unroll
    for (int tt = 0; tt < TPB; ++tt) {
        int q = tid + tt * 256;
        if (q < NT) {
            int o4 = q % W4, t = (q / W4) % T;
            float4 bv = Mpg4[(Jp + t) * W4 + o4];
#pragma unroll
            for (int am = 0; am < 4; ++am) {
                a[tt][am][0] = bv.x; a[tt][am][1] = bv.y;
                a[tt][am][2] = bv.z; a[tt][am][3] = bv.w;
            }
        }
    }
    __syncthreads();
    for (int k = 0; k < 3; ++k) {
        for (int e = tid; e < Cinp * W4; e += 256)
            MSL4[e] = Mpg4[k * Cinp * W4 + e];
        __syncthreads();
#pragma unroll
        for (int tt = 0; tt < TPB; ++tt) {
            int q = tid + tt * 256;
            if (q < NT) {
                int o4 = q % W4, t = (q / W4) % T, m4 = q / (W4 * T);
                int trow = t + k - 1;
                if (trow < 0) trow += T;
                if (trow >= T) trow -= T;
                const float4* xp = X2T4 + trow * Cinp * MCQ + m4;
                const float4* mp = MSL4 + o4;
#pragma unroll 4
                for (int cin = 0; cin < Cinp; ++cin) {
                    float4 x4 = xp[cin * MCQ];
                    float4 mv = mp[cin * W4];
#pragma unroll
                    for (int aq = 0; aq < 4; ++aq) {
                        float m = (aq == 0) ? mv.x : (aq == 1) ? mv.y : (aq == 2) ? mv.z : mv.w;
                        a[tt][0][aq] += x4.x * m;
                        a[tt][1][aq] += x4.y * m;
                        a[tt][2][aq] += x4.z * m;
                        a[tt][3][aq] += x4.w * m;
                    }
                }
            }
        }
        __syncthreads();
    }
#pragma unroll
    for (int tt = 0; tt < TPB; ++tt) {
        int q = tid + tt * 256;
        if (q < NT) {
            int o4 = q % W4, t = (q / W4) % T, m4 = q / (W4 * T);
#pragma unroll
            for (int am = 0; am < 4; ++am) {
                float4 o;
                o.x = a[tt][am][0]; o.y = a[tt][am][1];
                o.z = a[tt][am][2]; o.w = a[tt][am][3];
                G4w[((m4 * 4 + am) * T + t) * W4 + o4] = o;
            }
        }
    }
    __syncthreads();

    // ---- S-phase (r8-proven 1t x 4s tiles; pad columns carry -1e30 bias) ----
    for (int it = tid; it < MC * T * S4N; it += 256) {
        int s4 = it % S4N, t = (it / S4N) % T, mc = it / (S4N * T);
        float acc[4];
#pragma unroll
        for (int q = 0; q < 4; ++q)
            acc[q] = smem[OFF_G + (mc * T + t) * W + Jp + s4 * 4 + q];
        for (int j4 = 0; j4 < Jp / 4; ++j4) {
            int k = j4 / CQ, cinq = j4 % CQ;
            float4 g = G4[(mc * T + t) * W4 + j4];
#pragma unroll
            for (int q = 0; q < 4; ++q) {
                int s = s4 * 4 + q;
                int trow = s + k - 1;
                if (trow < 0) trow += T;
                if (trow >= T) trow -= T;
                float4 x4 = X2A4[(mc * T + trow) * CQ + cinq];
                acc[q] += g.x * x4.x + g.y * x4.y + g.z * x4.z + g.w * x4.w;
            }
        }
#pragma unroll
        for (int q = 0; q < 4; ++q)
            smem[OFF_S + (mc * T + t) * ST + s4 * 4 + q] = 0.0625f * acc[q];
    }
    __syncthreads();

    // ---- register single-pass softmax (reads T4, writes T; pads exp->0) ----
    for (int rid = tid; rid < MC * T; rid += 256) {
        int base = OFF_S + rid * ST;
        float pr[T4];
#pragma unroll
        for (int s = 0; s < T4; ++s) pr[s] = smem[base + s];
        float mx = -1e30f;
#pragma unroll
        for (int s = 0; s < T4; ++s) mx = fmaxf(mx, pr[s]);
        float sum = 0.f;
#pragma unroll
        for (int s = 0; s < T4; ++s) { pr[s] = __expf(pr[s] - mx); sum += pr[s]; }
        float inv = 1.f / sum;
#pragma unroll
        for (int s = 0; s < T; ++s) smem[base + s] = pr[s] * inv;
    }
    __syncthreads();

    float* accp = wsw + WS_ACC + c_accbase[c] * 128 + b * T * T;
    for (int e = tid; e < T * T; e += 256) {
        int t = e / T, s = e % T;
        float v = 0.f;
        for (int mc = 0; mc < vm; ++mc)
            v += smem[OFF_S + (mc * T + t) * ST + s];
        atomicAdd(&accp[e], v);
    }
}

// ---------------- Expand accumulated means to the full output ----------------
template<int P, int BR>
__device__ __forceinline__ void expand_body(const float* __restrict__ acc,
                                            float* __restrict__ outp) {
    constexpr int T = BR ? P : (L_ / P);
    for (int idx = threadIdx.x; idx < L_ * L_; idx += 256) {
        int r = idx / L_, c2 = idx % L_;
        int rt = BR ? (r % P) : (r / P);
        int ct = BR ? (c2 % P) : (c2 / P);
        outp[idx] = acc[rt * T + ct];
    }
}

__global__ __launch_bounds__(256) void expand_kernel(const float* __restrict__ ws,
                                                     float* __restrict__ out) {
    int c = blockIdx.x, b = blockIdx.y;
    int i = c / 6, br = (c % 6) / 3, l = c % 3;
    int p = 3 + 2 * i;
    int T = br ? p : (L_ / p);
    __shared__ float sAcc[1232];
    int abase = c_accbase[c] * 128 + b * T * T;
    for (int idx = threadIdx.x; idx < T * T; idx += 256)
        sAcc[idx] = ws[WS_ACC + abase + idx] * (1.f / (float)M_);
    __syncthreads();
    float* outp = out + ((size_t)(br * 9 + i * 3 + l) * B_ + (size_t)b) * (size_t)(L_ * L_);
    int key = i * 2 + br;
    switch (key) {
        case 0: expand_body<3, 0>(sAcc, outp); break;
        case 1: expand_body<3, 1>(sAcc, outp); break;
        case 2: expand_body<5, 0>(sAcc, outp); break;
        case 3: expand_body<5, 1>(sAcc, outp); break;
        case 4: expand_body<7, 0>(sAcc, outp); break;
        case 5: expand_body<7, 1>(sAcc, outp); break;
    }
}

extern "C" void kernel_launch(void* const* d_in, const int* in_sizes, int n_in,
                              void* d_out, int out_size, void* d_ws, size_t ws_size,
                              hipStream_t stream) {
    const float* x   = (const float*)d_in[0];
    const float* cp0 = (const float*)d_in[1];
    const float* cn0 = (const float*)d_in[2];
    const float* cp1 = (const float*)d_in[3];
    const float* cn1 = (const float*)d_in[4];
    const float* cp2 = (const float*)d_in[5];
    const float* cn2 = (const float*)d_in[6];
    const float* Wq  = (const float*)d_in[7];
    const float* bq  = (const float*)d_in[8];
    const float* Wk  = (const float*)d_in[9];
    const float* bk  = (const float*)d_in[10];
    float* ws = (float*)d_ws;
    float* out = (float*)d_out;

    const int use_partial = (ws_size >= WS_NEED_BYTES) ? 1 : 0;

    hipLaunchKernelGGL(revin_kernel, dim3(B_ * M_), dim3(128), 0, stream, x, ws);
    hipLaunchKernelGGL(pe_kernel, dim3(6), dim3(256), 0, stream, ws);
    if (use_partial) {
        hipLaunchKernelGGL(lr2_kernel, dim3(NCOMBO, 14, 4), dim3(256), 0, stream,
                           cp0, cn0, cp1, cn1, cp2, cn2, Wq, bq, Wk, bk, ws);
    } else {
        hipLaunchKernelGGL(lr_kernel, dim3(NCOMBO, 27), dim3(256), 0, stream,
                           cp0, cn0, cp1, cn1, cp2, cn2, Wq, bq, Wk, bk, ws);
    }
    hipLaunchKernelGGL(mm_kernel, dim3(NCOMBO, 49), dim3(256), 0, stream, ws, use_partial);
    hipLaunchKernelGGL(pack_kernel, dim3(NCOMBO), dim3(256), 0, stream, ws);
    hipLaunchKernelGGL(zero_acc, dim3((ACC_TOT / 4 + 255) / 256), dim3(256), 0, stream, ws);

    hipLaunchKernelGGL((attn2<3, 0>), dim3(B_, 3, 14), dim3(256), 0, stream, ws, ws); // MC=4
    hipLaunchKernelGGL((attn2<3, 1>), dim3(B_, 3, 5),  dim3(256), 0, stream, ws, ws); // MC=12
    hipLaunchKernelGGL((attn2<5, 0>), dim3(B_, 3, 14), dim3(256), 0, stream, ws, ws); // MC=4
    hipLaunchKernelGGL((attn2<5, 1>), dim3(B_, 3, 7),  dim3(256), 0, stream, ws, ws); // MC=8
    hipLaunchKernelGGL((attn2<7, 0>), dim3(B_, 3, 7),  dim3(256), 0, stream, ws, ws); // MC=8
    hipLaunchKernelGGL((attn2<7, 1>), dim3(B_, 3, 7),  dim3(256), 0, stream, ws, ws); // MC=8

    hipLaunchKernelGGL(expand_kernel, dim3(NCOMBO, B_), dim3(256), 0, stream, ws, out);
}

// Round 12
// 482.518 us; speedup vs baseline: 2.3610x; 1.0033x over previous
//
#include <hip/hip_runtime.h>
#include <hip/hip_bf16.h>

// Problem constants
#define B_ 128
#define L_ 105
#define M_ 55
#define D_ 256
#define NCOMBO 18   // 3 patches x 2 branches x 3 layers

// Workspace layout (float offsets)
#define WS_XT    0          // normalized x^T: [B*M][105] = 739200
#define WS_PE    739200     // pos-embed tables: 86*256 = 22016
#define WS_LEFT  761216     // 18 * 27648 (fallback path; MP overlays after mm)
#define WS_RIGHT 1258880    // 18 * 27648 (ACC overlays after mm)
#define WS_MM    1756544    // 18 * 11664
#define WS_MP    761216     // 18 * 12544 (over LEFT, after mm)
#define WS_ACC   1258880    // 758016 floats (over RIGHT + MM tail)
#define LR_STRIDE 27648
#define MM_STRIDE 11664
#define MP_STRIDE 12544
#define ACC_TOT  758016

// K-split partial region (only used when ws_size is large enough)
#define WS_LRP        1966592
#define LRP_KZ_STRIDE 27648
#define LRP_C_STRIDE  110592
#define LRP_HALF      1990656
#define WS_NEED_BYTES ((size_t)(WS_LRP + 2 * LRP_HALF) * 4)

__constant__ int c_peOff[6] = {0, 35, 38, 59, 64, 79};
__constant__ int c_accbase[18] = {0,1225,2450, 3675,3684,3693, 3702,4143,4584,
                                  5025,5050,5075, 5100,5325,5550, 5775,5824,5873};

__device__ __forceinline__ void combo_dims(int c, int& i, int& br, int& l,
                                           int& p, int& n, int& Cin, int& T, int& J) {
    i = c / 6; br = (c % 6) / 3; l = c % 3;
    p = 3 + 2 * i;
    n = L_ / p;
    Cin = br ? n : p;
    T   = br ? p : n;
    J = 3 * Cin;
}

__device__ __forceinline__ float dot4(float4 a, float4 b) {
    return a.x * b.x + a.y * b.y + a.z * b.z + a.w * b.w;
}

// ---------------- RevIN normalize ----------------
__global__ void revin_kernel(const float* __restrict__ x, float* __restrict__ ws) {
    int bm = blockIdx.x; int b = bm / M_; int m = bm % M_;
    int tid = threadIdx.x;
    __shared__ float s1[128], s2[128];
    float v = 0.f;
    if (tid < L_) v = x[(b * L_ + tid) * M_ + m];
    s1[tid] = v; s2[tid] = v * v;
    __syncthreads();
    for (int off = 64; off > 0; off >>= 1) {
        if (tid < off) { s1[tid] += s1[tid + off]; s2[tid] += s2[tid + off]; }
        __syncthreads();
    }
    float mean = s1[0] * (1.f / L_);
    float var  = s2[0] * (1.f / L_) - mean * mean;
    float rstd = rsqrtf(var + 1e-5f);
    if (tid < L_) ws[WS_XT + bm * L_ + tid] = (v - mean) * rstd;
}

// ---------------- Positional embedding tables ----------------
__global__ void pe_kernel(float* __restrict__ ws) {
    int bi = blockIdx.x;
    int i = bi / 2, br = bi % 2;
    int p = 3 + 2 * i, n = L_ / p;
    int T = br ? p : n;
    int d = threadIdx.x;
    float divv = expf(-(float)(d & ~1) * (logf(10000.f) / (float)D_));
    float* base = ws + WS_PE + c_peOff[bi] * D_;
    for (int t = 0; t < T; ++t) {
        float arg = (float)t * divv;
        base[t * D_ + d] = (d & 1) ? cosf(arg) : sinf(arg);
    }
}

// ---------------- lr2: K-split x4, 8-row tiles, unique-writer partials ----------------
__global__ __launch_bounds__(256) void lr2_kernel(
                          const float* __restrict__ w0, const float* __restrict__ w1,
                          const float* __restrict__ w2c, const float* __restrict__ w3,
                          const float* __restrict__ w4, const float* __restrict__ w5,
                          const float* __restrict__ Wq, const float* __restrict__ bq,
                          const float* __restrict__ Wk, const float* __restrict__ bk,
                          float* __restrict__ ws) {
    int c = blockIdx.x;
    int i, br, l, p, n, Cin, T, J; combo_dims(c, i, br, l, p, n, Cin, T, J);
    int Mdim = J + T;
    int r0 = blockIdx.y * 8;
    if (r0 >= Mdim) return;
    int kz = blockIdx.z;
    int d0 = kz * 64;
    int wi = i * 2 + br;
    const float* conv = (wi == 0) ? w0 : (wi == 1) ? w1 : (wi == 2) ? w2c
                       : (wi == 3) ? w3 : (wi == 4) ? w4 : w5;
    __shared__ float S[8][64];
    int tid = threadIdx.x;
    for (int idx = tid; idx < 8 * 64; idx += 256) {
        int rr = idx >> 6, dd = idx & 63;
        int row = r0 + rr; float val = 0.f;
        int d = d0 + dd;
        if (row < J) val = conv[d * J + row];
        else if (row < Mdim) val = ws[WS_PE + (c_peOff[wi] + (row - J)) * D_ + d];
        S[rr][dd] = val;
    }
    __syncthreads();
    const float* wqp = Wq + l * D_ * D_;
    const float* wkp = Wk + l * D_ * D_;
    float accL[8], accR[8];
#pragma unroll
    for (int rr = 0; rr < 8; ++rr) { accL[rr] = 0.f; accR[rr] = 0.f; }
    int o = tid;
#pragma unroll 8
    for (int dd = 0; dd < 64; ++dd) {
        int d = d0 + dd;
        float wqv = wqp[d * D_ + o];
        float wkv = wkp[d * D_ + o];
#pragma unroll
        for (int rr = 0; rr < 8; ++rr) {
            float sv = S[rr][dd];
            accL[rr] += sv * wqv;
            accR[rr] += sv * wkv;
        }
    }
    float bqv = (kz == 0) ? bq[l * D_ + o] : 0.f;
    float bkv = (kz == 0) ? bk[l * D_ + o] : 0.f;
    float* Lp = ws + WS_LRP + c * LRP_C_STRIDE + kz * LRP_KZ_STRIDE;
    float* Rp = Lp + LRP_HALF;
#pragma unroll
    for (int rr = 0; rr < 8; ++rr) {
        int row = r0 + rr;
        if (row < Mdim) {
            float aq = (row >= J) ? bqv : 0.f;
            float ak = (row >= J) ? bkv : 0.f;
            Lp[row * D_ + o] = accL[rr] + aq;
            Rp[row * D_ + o] = accR[rr] + ak;
        }
    }
}

// ---------------- Fallback lr: 4 rows per block, full K ----------------
__global__ __launch_bounds__(256) void lr_kernel(
                          const float* __restrict__ w0, const float* __restrict__ w1,
                          const float* __restrict__ w2c, const float* __restrict__ w3,
                          const float* __restrict__ w4, const float* __restrict__ w5,
                          const float* __restrict__ Wq, const float* __restrict__ bq,
                          const float* __restrict__ Wk, const float* __restrict__ bk,
                          float* __restrict__ ws) {
    int c = blockIdx.x;
    int i, br, l, p, n, Cin, T, J; combo_dims(c, i, br, l, p, n, Cin, T, J);
    int Mdim = J + T;
    int r0 = blockIdx.y * 4;
    if (r0 >= Mdim) return;
    int wi = i * 2 + br;
    const float* conv = (wi == 0) ? w0 : (wi == 1) ? w1 : (wi == 2) ? w2c
                       : (wi == 3) ? w3 : (wi == 4) ? w4 : w5;
    __shared__ float S[4][256];
    int tid = threadIdx.x;
    for (int idx = tid; idx < 4 * 256; idx += 256) {
        int rr = idx >> 8, dd = idx & 255;
        int row = r0 + rr; float val = 0.f;
        if (row < J) val = conv[dd * J + row];
        else if (row < Mdim) val = ws[WS_PE + (c_peOff[wi] + (row - J)) * D_ + dd];
        S[rr][dd] = val;
    }
    __syncthreads();
    const float* wqp = Wq + l * D_ * D_;
    const float* wkp = Wk + l * D_ * D_;
    float accL[4], accR[4];
#pragma unroll
    for (int rr = 0; rr < 4; ++rr) { accL[rr] = 0.f; accR[rr] = 0.f; }
    int o = tid;
#pragma unroll 8
    for (int d = 0; d < D_; ++d) {
        float wqv = wqp[d * D_ + o];
        float wkv = wkp[d * D_ + o];
#pragma unroll
        for (int rr = 0; rr < 4; ++rr) {
            float sv = S[rr][d];
            accL[rr] += sv * wqv;
            accR[rr] += sv * wkv;
        }
    }
    float bqv = bq[l * D_ + o], bkv = bk[l * D_ + o];
#pragma unroll
    for (int rr = 0; rr < 4; ++rr) {
        int row = r0 + rr;
        if (row < Mdim) {
            float aq = (row >= J) ? bqv : 0.f;
            float ak = (row >= J) ? bkv : 0.f;
            ws[WS_LEFT  + c * LR_STRIDE + row * D_ + o] = accL[rr] + aq;
            ws[WS_RIGHT + c * LR_STRIDE + row * D_ + o] = accR[rr] + ak;
        }
    }
}

// ---------------- M' = Left @ Right^T (sums K-split partials when enabled) ------------
__global__ void mm_kernel(float* __restrict__ ws, int use_partial) {
    int c = blockIdx.x;
    int i, br, l, p, n, Cin, T, J; combo_dims(c, i, br, l, p, n, Cin, T, J);
    int Mdim = J + T;
    int tr = blockIdx.y / 7, tc = blockIdx.y % 7;
    int r0 = tr * 16, c0 = tc * 16;
    if (r0 >= Mdim || c0 >= Mdim) return;
    __shared__ __align__(16) float Lb[16][260], Rb[16][260];
    int tid = threadIdx.x;
    if (use_partial) {
        const float* Lp = ws + WS_LRP + c * LRP_C_STRIDE;
        const float* Rp = Lp + LRP_HALF;
        for (int idx = tid; idx < 16 * 256; idx += 256) {
            int rr = idx >> 8, d = idx & 255;
            int rL = r0 + rr, rR = c0 + rr;
            float lv = 0.f, rv = 0.f;
            if (rL < Mdim) {
                int base = rL * D_ + d;
                lv = Lp[base] + Lp[base + LRP_KZ_STRIDE]
                   + Lp[base + 2 * LRP_KZ_STRIDE] + Lp[base + 3 * LRP_KZ_STRIDE];
            }
            if (rR < Mdim) {
                int base = rR * D_ + d;
                rv = Rp[base] + Rp[base + LRP_KZ_STRIDE]
                   + Rp[base + 2 * LRP_KZ_STRIDE] + Rp[base + 3 * LRP_KZ_STRIDE];
            }
            Lb[rr][d] = lv; Rb[rr][d] = rv;
        }
    } else {
        for (int idx = tid; idx < 16 * 256; idx += 256) {
            int rr = idx >> 8, d = idx & 255;
            int rL = r0 + rr, rR = c0 + rr;
            Lb[rr][d] = (rL < Mdim) ? ws[WS_LEFT  + c * LR_STRIDE + rL * D_ + d] : 0.f;
            Rb[rr][d] = (rR < Mdim) ? ws[WS_RIGHT + c * LR_STRIDE + rR * D_ + d] : 0.f;
        }
    }
    __syncthreads();
    int rr = tid / 16, cc = tid % 16;
    const float4* lrow = (const float4*)(&Lb[rr][0]);
    const float4* rrow = (const float4*)(&Rb[cc][0]);
    float acc = 0.f;
#pragma unroll 8
    for (int d4 = 0; d4 < 64; ++d4) {
        float4 a = lrow[d4], bb = rrow[d4];
        acc += a.x * bb.x + a.y * bb.y + a.z * bb.z + a.w * bb.w;
    }
    int r = r0 + rr, cth = c0 + cc;
    if (r < Mdim && cth < Mdim)
        ws[WS_MM + c * MM_STRIDE + r * Mdim + cth] = acc;
}

// ---------------- Pack M' into reordered/padded Mp [W x W] per combo ----------------
__global__ void pack_kernel(float* __restrict__ ws) {
    int c = blockIdx.x;
    int i, br, l, p, n, Cin, T, J; combo_dims(c, i, br, l, p, n, Cin, T, J);
    int Mdim = J + T;
    int Cinp = (Cin + 3) & ~3;
    int Jp = 3 * Cinp;
    int T4 = (T + 3) & ~3;
    int W = Jp + T4;
    const float* MMc = ws + WS_MM + c * MM_STRIDE;
    float* Mp = ws + WS_MP + c * MP_STRIDE;
    for (int e = threadIdx.x; e < W * W; e += 256) {
        int r = e / W, o = e % W;
        int srcr = -1, srcc = -1;
        bool brow = false;
        if (r < Jp) {
            int k = r / Cinp, cin = r % Cinp;
            if (cin < Cin) srcr = cin * 3 + k;
        } else {
            int t = r - Jp;
            if (t < T) { srcr = J + t; brow = true; }
        }
        if (o < Jp) {
            int k2 = o / Cinp, cin2 = o % Cinp;
            if (cin2 < Cin) srcc = cin2 * 3 + k2;
        } else {
            int s = o - Jp;
            if (s < T) srcc = J + s;
        }
        float val;
        if (srcr >= 0 && srcc >= 0) val = MMc[srcr * Mdim + srcc];
        else if (brow && o >= Jp && srcc < 0) val = -1e30f;  // padded-s bias: kill in softmax
        else val = 0.f;
        Mp[e] = val;
    }
}

// ---------------- Zero the atomic accumulator region ----------------
__global__ void zero_acc(float* __restrict__ ws) {
    int idx = blockIdx.x * 256 + threadIdx.x;
    if (idx < ACC_TOT / 4) {
        float4 z; z.x = 0.f; z.y = 0.f; z.z = 0.f; z.w = 0.f;
        ((float4*)(ws + WS_ACC))[idx] = z;
    }
}

// ---------------- Fused attention (r8 structure + t-split for P=3/BR=0) ----------
template<int P, int BR>
__global__ __launch_bounds__(256) void attn2(const float* __restrict__ ws,
                                             float* __restrict__ wsw) {
    constexpr int N    = L_ / P;
    constexpr int Cin  = BR ? N : P;
    constexpr int T    = BR ? P : N;
    constexpr int Cinp = (Cin + 3) & ~3;
    constexpr int Jp   = 3 * Cinp;
    constexpr int T4   = (T + 3) & ~3;
    constexpr int W    = Jp + T4;
    constexpr int W4   = W / 4;
    constexpr int ST   = T4 + 1;
    constexpr int II   = (P - 3) / 2;
    constexpr int MC   = BR ? (P == 3 ? 12 : 8) : (P == 7 ? 8 : 4);
    constexpr int TH   = (BR == 0 && P == 3) ? 2 : 1;     // t-split factor
    constexpr int TSUB = (T + TH - 1) / TH;               // rows per t-half
    constexpr int NT   = (MC / 4) * TSUB * W4;
    constexpr int TPB  = (NT + 255) / 256;
    constexpr int MCQ  = MC / 4;
    constexpr int CQ   = Cinp / 4;
    constexpr int S4N  = T4 / 4;
    constexpr int OFF_X2T = 0;
    constexpr int OFF_X2A = OFF_X2T + T * Cinp * MC;
    constexpr int OFF_MSL = OFF_X2A + T * Cinp * MC;
    constexpr int OFF_G   = OFF_MSL + Cinp * W;
    constexpr int OFF_S   = OFF_G + MC * TSUB * W;
    constexpr int TOT     = OFF_S + MC * TSUB * ST;
    static_assert(TOT * 4 <= 65536, "LDS budget");

    __shared__ __align__(16) float smem[TOT];
    const int tid = threadIdx.x;
    const int b = blockIdx.x, l = blockIdx.y;
    const int sp = blockIdx.z / TH;
    const int th = blockIdx.z % TH;
    const int t0 = th * TSUB;
    const int TC = (T - t0 < TSUB) ? (T - t0) : TSUB;     // valid t rows this block
    const int c = II * 6 + BR * 3 + l;
    const int m0 = sp * MC;
    const int vm = (M_ - m0 < MC) ? (M_ - m0) : MC;

    const float*  Mpg  = ws + WS_MP + c * MP_STRIDE;
    const float4* Mpg4 = (const float4*)Mpg;

    for (int e = tid; e < T * Cinp * MC; e += 256) {
        int mcol = e % MC, rest = e / MC;
        int cin = rest % Cinp, trow = rest / Cinp;
        float v = 0.f;
        if (cin < Cin && m0 + mcol < M_)
            v = ws[WS_XT + (size_t)(b * M_ + m0 + mcol) * L_ + trow * Cin + cin];
        smem[OFF_X2T + e] = v;
    }
    for (int e = tid; e < T * Cinp * MC; e += 256) {
        int cin = e % Cinp, trow = (e / Cinp) % T, mcol = e / (Cinp * T);
        float v = 0.f;
        if (cin < Cin && m0 + mcol < M_)
            v = ws[WS_XT + (size_t)(b * M_ + m0 + mcol) * L_ + trow * Cin + cin];
        smem[OFF_X2A + e] = v;
    }

    const float4* X2T4 = (const float4*)(smem + OFF_X2T);
    const float4* X2A4 = (const float4*)(smem + OFF_X2A);
    float4*       MSL4 = (float4*)(smem + OFF_MSL);
    float4*       G4w  = (float4*)(smem + OFF_G);
    const float4* G4   = (const float4*)(smem + OFF_G);

    // ---- G-phase: register-tiled GEMM over this block's t rows ----
    float a[TPB][4][4];
#pragma unroll
    for (int tt = 0; tt < TPB; ++tt) {
        int q = tid + tt * 256;
        if (q < NT) {
            int o4 = q % W4, tl = (q / W4) % TSUB;
            if (tl < TC) {
                float4 bv = Mpg4[(Jp + t0 + tl) * W4 + o4];
#pragma unroll
                for (int am = 0; am < 4; ++am) {
                    a[tt][am][0] = bv.x; a[tt][am][1] = bv.y;
                    a[tt][am][2] = bv.z; a[tt][am][3] = bv.w;
                }
            }
        }
    }
    __syncthreads();
    for (int k = 0; k < 3; ++k) {
        for (int e = tid; e < Cinp * W4; e += 256)
            MSL4[e] = Mpg4[k * Cinp * W4 + e];
        __syncthreads();
#pragma unroll
        for (int tt = 0; tt < TPB; ++tt) {
            int q = tid + tt * 256;
            if (q < NT) {
                int o4 = q % W4, tl = (q / W4) % TSUB, m4 = q / (W4 * TSUB);
                if (tl < TC) {
                    int trow = t0 + tl + k - 1;
                    if (trow < 0) trow += T;
                    if (trow >= T) trow -= T;
                    const float4* xp = X2T4 + trow * Cinp * MCQ + m4;
                    const float4* mp = MSL4 + o4;
#pragma unroll 4
                    for (int cin = 0; cin < Cinp; ++cin) {
                        float4 x4 = xp[cin * MCQ];
                        float4 mv = mp[cin * W4];
#pragma unroll
                        for (int aq = 0; aq < 4; ++aq) {
                            float m = (aq == 0) ? mv.x : (aq == 1) ? mv.y
                                    : (aq == 2) ? mv.z : mv.w;
                            a[tt][0][aq] += x4.x * m;
                            a[tt][1][aq] += x4.y * m;
                            a[tt][2][aq] += x4.z * m;
                            a[tt][3][aq] += x4.w * m;
                        }
                    }
                }
            }
        }
        __syncthreads();
    }
#pragma unroll
    for (int tt = 0; tt < TPB; ++tt) {
        int q = tid + tt * 256;
        if (q < NT) {
            int o4 = q % W4, tl = (q / W4) % TSUB, m4 = q / (W4 * TSUB);
            if (tl < TC) {
#pragma unroll
                for (int am = 0; am < 4; ++am) {
                    float4 o;
                    o.x = a[tt][am][0]; o.y = a[tt][am][1];
                    o.z = a[tt][am][2]; o.w = a[tt][am][3];
                    G4w[((m4 * 4 + am) * TSUB + tl) * W4 + o4] = o;
                }
            }
        }
    }
    __syncthreads();

    // ---- S-phase: 1t x 4s tiles (pad columns carry -1e30 bias) ----
    for (int it = tid; it < MC * TC * S4N; it += 256) {
        int s4 = it % S4N, tl = (it / S4N) % TC, mc = it / (S4N * TC);
        float acc[4];
#pragma unroll
        for (int q = 0; q < 4; ++q)
            acc[q] = smem[OFF_G + (mc * TSUB + tl) * W + Jp + s4 * 4 + q];
        for (int j4 = 0; j4 < Jp / 4; ++j4) {
            int k = j4 / CQ, cinq = j4 % CQ;
            float4 g = G4[(mc * TSUB + tl) * W4 + j4];
#pragma unroll
            for (int q = 0; q < 4; ++q) {
                int s = s4 * 4 + q;
                int trow = s + k - 1;
                if (trow < 0) trow += T;
                if (trow >= T) trow -= T;
                float4 x4 = X2A4[(mc * T + trow) * CQ + cinq];
                acc[q] += g.x * x4.x + g.y * x4.y + g.z * x4.z + g.w * x4.w;
            }
        }
#pragma unroll
        for (int q = 0; q < 4; ++q)
            smem[OFF_S + (mc * TSUB + tl) * ST + s4 * 4 + q] = 0.0625f * acc[q];
    }
    __syncthreads();

    // ---- register single-pass softmax (reads T4, writes T; pads exp->0) ----
    for (int rid = tid; rid < MC * TC; rid += 256) {
        int mc = rid / TC, tl = rid % TC;
        int base = OFF_S + (mc * TSUB + tl) * ST;
        float pr[T4];
#pragma unroll
        for (int s = 0; s < T4; ++s) pr[s] = smem[base + s];
        float mx = -1e30f;
#pragma unroll
        for (int s = 0; s < T4; ++s) mx = fmaxf(mx, pr[s]);
        float sum = 0.f;
#pragma unroll
        for (int s = 0; s < T4; ++s) { pr[s] = __expf(pr[s] - mx); sum += pr[s]; }
        float inv = 1.f / sum;
#pragma unroll
        for (int s = 0; s < T; ++s) smem[base + s] = pr[s] * inv;
    }
    __syncthreads();

    float* accp = wsw + WS_ACC + c_accbase[c] * 128 + b * T * T;
    for (int e = tid; e < TC * T; e += 256) {
        int tl = e / T, s = e % T;
        float v = 0.f;
        for (int mc = 0; mc < vm; ++mc)
            v += smem[OFF_S + (mc * TSUB + tl) * ST + s];
        atomicAdd(&accp[(t0 + tl) * T + s], v);
    }
}

// ---------------- Expand accumulated means to the full output ----------------
template<int P, int BR>
__device__ __forceinline__ void expand_body(const float* __restrict__ acc,
                                            float* __restrict__ outp) {
    constexpr int T = BR ? P : (L_ / P);
    for (int idx = threadIdx.x; idx < L_ * L_; idx += 256) {
        int r = idx / L_, c2 = idx % L_;
        int rt = BR ? (r % P) : (r / P);
        int ct = BR ? (c2 % P) : (c2 / P);
        outp[idx] = acc[rt * T + ct];
    }
}

__global__ __launch_bounds__(256) void expand_kernel(const float* __restrict__ ws,
                                                     float* __restrict__ out) {
    int c = blockIdx.x, b = blockIdx.y;
    int i = c / 6, br = (c % 6) / 3, l = c % 3;
    int p = 3 + 2 * i;
    int T = br ? p : (L_ / p);
    __shared__ float sAcc[1232];
    int abase = c_accbase[c] * 128 + b * T * T;
    for (int idx = threadIdx.x; idx < T * T; idx += 256)
        sAcc[idx] = ws[WS_ACC + abase + idx] * (1.f / (float)M_);
    __syncthreads();
    float* outp = out + ((size_t)(br * 9 + i * 3 + l) * B_ + (size_t)b) * (size_t)(L_ * L_);
    int key = i * 2 + br;
    switch (key) {
        case 0: expand_body<3, 0>(sAcc, outp); break;
        case 1: expand_body<3, 1>(sAcc, outp); break;
        case 2: expand_body<5, 0>(sAcc, outp); break;
        case 3: expand_body<5, 1>(sAcc, outp); break;
        case 4: expand_body<7, 0>(sAcc, outp); break;
        case 5: expand_body<7, 1>(sAcc, outp); break;
    }
}

extern "C" void kernel_launch(void* const* d_in, const int* in_sizes, int n_in,
                              void* d_out, int out_size, void* d_ws, size_t ws_size,
                              hipStream_t stream) {
    const float* x   = (const float*)d_in[0];
    const float* cp0 = (const float*)d_in[1];
    const float* cn0 = (const float*)d_in[2];
    const float* cp1 = (const float*)d_in[3];
    const float* cn1 = (const float*)d_in[4];
    const float* cp2 = (const float*)d_in[5];
    const float* cn2 = (const float*)d_in[6];
    const float* Wq  = (const float*)d_in[7];
    const float* bq  = (const float*)d_in[8];
    const float* Wk  = (const float*)d_in[9];
    const float* bk  = (const float*)d_in[10];
    float* ws = (float*)d_ws;
    float* out = (float*)d_out;

    const int use_partial = (ws_size >= WS_NEED_BYTES) ? 1 : 0;

    hipLaunchKernelGGL(revin_kernel, dim3(B_ * M_), dim3(128), 0, stream, x, ws);
    hipLaunchKernelGGL(pe_kernel, dim3(6), dim3(256), 0, stream, ws);
    if (use_partial) {
        hipLaunchKernelGGL(lr2_kernel, dim3(NCOMBO, 14, 4), dim3(256), 0, stream,
                           cp0, cn0, cp1, cn1, cp2, cn2, Wq, bq, Wk, bk, ws);
    } else {
        hipLaunchKernelGGL(lr_kernel, dim3(NCOMBO, 27), dim3(256), 0, stream,
                           cp0, cn0, cp1, cn1, cp2, cn2, Wq, bq, Wk, bk, ws);
    }
    hipLaunchKernelGGL(mm_kernel, dim3(NCOMBO, 49), dim3(256), 0, stream, ws, use_partial);
    hipLaunchKernelGGL(pack_kernel, dim3(NCOMBO), dim3(256), 0, stream, ws);
    hipLaunchKernelGGL(zero_acc, dim3((ACC_TOT / 4 + 255) / 256), dim3(256), 0, stream, ws);

    // z = m-splits x t-halves (TH=2 for <3,0> only)
    hipLaunchKernelGGL((attn2<3, 0>), dim3(B_, 3, 28), dim3(256), 0, stream, ws, ws); // MC=4,TH=2
    hipLaunchKernelGGL((attn2<3, 1>), dim3(B_, 3, 5),  dim3(256), 0, stream, ws, ws); // MC=12
    hipLaunchKernelGGL((attn2<5, 0>), dim3(B_, 3, 14), dim3(256), 0, stream, ws, ws); // MC=4
    hipLaunchKernelGGL((attn2<5, 1>), dim3(B_, 3, 7),  dim3(256), 0, stream, ws, ws); // MC=8
    hipLaunchKernelGGL((attn2<7, 0>), dim3(B_, 3, 7),  dim3(256), 0, stream, ws, ws); // MC=8
    hipLaunchKernelGGL((attn2<7, 1>), dim3(B_, 3, 7),  dim3(256), 0, stream, ws, ws); // MC=8

    hipLaunchKernelGGL(expand_kernel, dim3(NCOMBO, B_), dim3(256), 0, stream, ws, out);
}